// Round 13
// baseline (424.095 us; speedup 1.0000x reference)
//
#include <hip/hip_runtime.h>

#define NN 100000
#define NE 1600000
#define NP 100096   // 391 * 256 rows, GEMM tile padding
#define NBKT 391    // ceil(NN/256) coarse buckets
#define CAP 6144    // padded region capacity per bucket
#define EPSV 1e-5f

typedef unsigned int u32;
typedef unsigned short u16;
typedef unsigned long long u64;
typedef __bf16 bf16x8 __attribute__((ext_vector_type(8)));
typedef float f32x4 __attribute__((ext_vector_type(4)));

#define GLBP(x) ((const __attribute__((address_space(1))) u32*)(x))
#define LDSP(x) ((__attribute__((address_space(3))) u32*)(x))

__device__ __forceinline__ u16 f2bf(float f) {
  u32 x = __float_as_uint(f);
  return (u16)((x + 0x7FFFu + ((x >> 16) & 1u)) >> 16);  // RNE
}
__device__ __forceinline__ float bf2f(u16 h) { return __uint_as_float(((u32)h) << 16); }
__device__ __forceinline__ u32 pk2(float a, float b) {
  return (u32)f2bf(a) | ((u32)f2bf(b) << 16);
}
__device__ __forceinline__ float sigm(float x) { return 1.f / (1.f + __expf(-x)); }

// ---------------- setup A: wfuse (blocks 0..143) | pack emb (144..151)
__device__ __forceinline__ void pack_one(const float* W, u32* out, int K, int KOT, int i) {
  int q = i & 3, lane = (i >> 2) & 63, f = i >> 8;
  int ks = f / KOT, ot = f - ks * KOT;
  int o = ot * 16 + (lane & 15);
  int k = ks * 32 + (lane >> 4) * 8 + q * 2;
  out[i] = pk2(W[o * K + k], W[o * K + k + 1]);
}

__global__ void setupA(const float* __restrict__ relw, const float* __restrict__ Wih,
                       const float* __restrict__ embW,
                       float* __restrict__ Wrow, u32* __restrict__ PWem) {
  int b = blockIdx.x;
  if (b < 144) {
    int t = b * 256 + threadIdx.x;
    if (t >= 192 * 192) return;
    int kg = t / 192, j = t % 192;
    const float* a = relw + (j >> 6) * 4096 + (j & 63) * 64;
    const float* w = Wih + kg * 64;
    float s = 0.f;
#pragma unroll
    for (int k = 0; k < 64; ++k) s += a[k] * w[k];
    Wrow[kg * 192 + j] = s;
  } else {
    pack_one(embW, PWem, 64, 4, (b - 144) * 256 + threadIdx.x);
  }
}

// L1 gate panels: [3 gates][24 frags] from Wrow rows g*64..g*64+63, K=192
__global__ void pack_g1(const float* __restrict__ Wrow, u32* __restrict__ P) {
  int i = blockIdx.x * 256 + threadIdx.x;  // 18432
  int q = i & 3, lane = (i >> 2) & 63, f = i >> 8;
  int g = f / 24, fl = f - g * 24;
  int ks = fl >> 2, o = fl & 3;
  int row = g * 64 + o * 16 + (lane & 15);
  int k = ks * 32 + (lane >> 4) * 8 + q * 2;
  P[i] = pk2(Wrow[row * 192 + k], Wrow[row * 192 + k + 1]);
}

// L2 gate panels: [4 gates][32 frags], K=256 = [swh(192) | h(64)]
// gates: 0=r,1=z (both parts), 2=in (swh only), 3=hn (h only)
__global__ void pack_g2(const float* __restrict__ Wrow, const float* __restrict__ Whh,
                        u32* __restrict__ P) {
  int i = blockIdx.x * 256 + threadIdx.x;  // 32768
  int q = i & 3, lane = (i >> 2) & 63, f = i >> 8;
  int g = f >> 5, fl = f & 31;
  int ks = fl >> 2, o = fl & 3;
  u32 val = 0u;
  if (ks < 6) {
    if (g < 3) {
      int row = g * 64 + o * 16 + (lane & 15);
      int k = ks * 32 + (lane >> 4) * 8 + q * 2;
      val = pk2(Wrow[row * 192 + k], Wrow[row * 192 + k + 1]);
    }
  } else {
    int g2 = (g < 2) ? g : (g == 3 ? 2 : -1);
    if (g2 >= 0) {
      int row = g2 * 64 + o * 16 + (lane & 15);
      int k = (ks - 6) * 32 + (lane >> 4) * 8 + q * 2;
      val = pk2(Whh[row * 64 + k], Whh[row * 64 + k + 1]);
    }
  }
  P[i] = val;
}

// pack BOTH head weights (128 rows) folded with inline ker-BN scale
__global__ void fold_pack(const float* __restrict__ Wa, const float* __restrict__ Wb,
                          const float* __restrict__ kacc, const float* __restrict__ kg,
                          u32* __restrict__ P) {
  int i = blockIdx.x * 256 + threadIdx.x;  // 4096
  int q = i & 3, lane = (i >> 2) & 63, f = i >> 8;
  int ks = f >> 3, ot = f & 7;
  int o = ot * 16 + (lane & 15);
  int k = ks * 32 + (lane >> 4) * 8 + q * 2;
  const float* W = (o < 64) ? (Wa + o * 64) : (Wb + (o - 64) * 64);
  const float inv = 1.f / NN;
  float m0 = kacc[k] * inv;
  float s0 = kg[k] * rsqrtf(kacc[64 + k] * inv - m0 * m0 + EPSV);
  float m1 = kacc[k + 1] * inv;
  float s1 = kg[k + 1] * rsqrtf(kacc[64 + k + 1] * inv - m1 * m1 + EPSV);
  P[i] = pk2(W[k] * s0, W[k + 1] * s1);
}

// ---------------------------------------------------------------------------
// Hierarchical CSR build (unchanged from r12)
// ---------------------------------------------------------------------------
__global__ __launch_bounds__(256) void countplace(const int* __restrict__ src,
                                                  const int* __restrict__ dst,
                                                  const int* __restrict__ rt,
                                                  const float* __restrict__ nrm,
                                                  int* __restrict__ gcnt,
                                                  u64* __restrict__ region) {
  __shared__ u32 hist[NBKT], gbase[NBKT];
  const int t = threadIdx.x;
  for (int i = t; i < NBKT; i += 256) hist[i] = 0;
  __syncthreads();
  const int e0 = blockIdx.x * 2048 + t;
  u32 rlo[8], rhi[8], lrank[8];
  int bkt[8];
#pragma unroll
  for (int i = 0; i < 8; ++i) {
    int e = e0 + i * 256;
    bkt[i] = -1;
    if (e < NE) {
      int d = dst[e];
      int b = d >> 8;
      bkt[i] = b;
      lrank[i] = atomicAdd(&hist[b], 1u);
      rlo[i] = (u32)src[e] | ((u32)rt[e] << 20) | ((u32)(d & 255) << 22);
      rhi[i] = __float_as_uint(nrm[e]);
    }
  }
  __syncthreads();
  for (int i = t; i < NBKT; i += 256) {
    u32 h = hist[i];
    gbase[i] = h ? (u32)atomicAdd(&gcnt[i], (int)h) : 0u;
  }
  __syncthreads();
#pragma unroll
  for (int i = 0; i < 8; ++i) {
    if (bkt[i] >= 0) {
      u32 pos = gbase[bkt[i]] + lrank[i];
      if (pos < CAP)
        region[(size_t)bkt[i] * CAP + pos] = (u64)rlo[i] | ((u64)rhi[i] << 32);
    }
  }
}

__global__ __launch_bounds__(512) void bucketscan(const int* __restrict__ gcnt,
                                                  int* __restrict__ bbase) {
  int t = threadIdx.x;
  int v = (t < NBKT) ? (gcnt[t] + 768) : 0;
  __shared__ int sh[512];
  sh[t] = v;
  __syncthreads();
#pragma unroll
  for (int off = 1; off < 512; off <<= 1) {
    int u = (t >= off) ? sh[t - off] : 0;
    __syncthreads();
    sh[t] += u;
    __syncthreads();
  }
  if (t < NBKT) bbase[t] = sh[t] - v;  // exclusive
}

__global__ __launch_bounds__(256) void localsort(const int* __restrict__ gcnt,
                                                 const int* __restrict__ bbase,
                                                 const u64* __restrict__ region,
                                                 u64* __restrict__ csr,
                                                 int* __restrict__ rowpr) {
  const int b = blockIdx.x, t = threadIdx.x;
  int n = gcnt[b];
  if (n > CAP) n = CAP;
  const int base = bbase[b];
  __shared__ u32 hist[1024], sc[256];
#pragma unroll
  for (int i = 0; i < 4; ++i) hist[t + 256 * i] = 0;
  __syncthreads();
  for (int i = t; i < n; i += 256)
    atomicAdd(&hist[(u32)(region[(size_t)b * CAP + i] >> 20) & 1023u], 1u);
  __syncthreads();
  u32 a0 = hist[4 * t], a1 = hist[4 * t + 1], a2 = hist[4 * t + 2];
  u32 p0 = (a0 + 1) & ~1u, p1 = (a1 + 1) & ~1u, p2 = (a2 + 1) & ~1u;
  u32 part = p0 + p1 + p2;
  sc[t] = part;
  __syncthreads();
#pragma unroll
  for (int off = 1; off < 256; off <<= 1) {
    u32 u = (t >= off) ? sc[t - off] : 0;
    __syncthreads();
    sc[t] += u;
    __syncthreads();
  }
  u32 ex = sc[t] - part;
  int node = b * 256 + t;
  rowpr[4 * node + 0] = base + (int)ex;
  rowpr[4 * node + 1] = base + (int)(ex + p0);
  rowpr[4 * node + 2] = base + (int)(ex + p0 + p1);
  rowpr[4 * node + 3] = base + (int)(ex + p0 + p1 + p2);
  __syncthreads();
  hist[4 * t + 0] = ex;
  hist[4 * t + 1] = ex + p0;
  hist[4 * t + 2] = ex + p0 + p1;
  __syncthreads();
  for (int i = t; i < n; i += 256) {
    u64 rec = region[(size_t)b * CAP + i];
    u32 pos = atomicAdd(&hist[(u32)(rec >> 20) & 1023u], 1u);
    csr[(size_t)base + pos] = rec;
  }
  __syncthreads();
  if (a0 & 1) csr[(size_t)base + ex + a0] = 0ull;
  if (a1 & 1) csr[(size_t)base + ex + p0 + a1] = 0ull;
  if (a2 & 1) csr[(size_t)base + ex + p0 + p1 + a2] = 0ull;
}

// ---------------- CSR gather (unchanged from r12) ----------------
__global__ __launch_bounds__(256) void csr_gather(const int* __restrict__ rowpr,
                                                  const u64* __restrict__ csr,
                                                  const u16* __restrict__ Xbf,
                                                  u16* __restrict__ ACCbf) {
  int wv = blockIdx.x * 4 + (threadIdx.x >> 6);
  int lane = threadIdx.x & 63;
  if (wv >= NN) return;
  const int half = lane >> 5, c2 = lane & 31;
  int4 rp = *reinterpret_cast<const int4*>(rowpr + 4 * wv);
  const int b0 = __builtin_amdgcn_readfirstlane(rp.x);
  const int b1 = __builtin_amdgcn_readfirstlane(rp.y);
  const int b2 = __builtin_amdgcn_readfirstlane(rp.z);
  const int b3 = __builtin_amdgcn_readfirstlane(rp.w);
  const u32* X4 = (const u32*)Xbf;
  float a0x = 0.f, a0y = 0.f, a1x = 0.f, a1y = 0.f, a2x = 0.f, a2y = 0.f;
#define PAIRB(J, AX, AY)                                                        \
  { u32 sA = (u32)__builtin_amdgcn_readlane((int)lo, (J));                      \
    u32 sB = (u32)__builtin_amdgcn_readlane((int)lo, (J) + 1);                  \
    u32 nA = (u32)__builtin_amdgcn_readlane((int)hi, (J));                      \
    u32 nB = (u32)__builtin_amdgcn_readlane((int)hi, (J) + 1);                  \
    u32 srp = half ? sB : sA;                                                   \
    float nm = __uint_as_float(half ? nB : nA);                                 \
    u32 xw = X4[((srp & 0xFFFFFu) << 5) | (u32)c2];                             \
    AX = fmaf(__uint_as_float(xw << 16), nm, AX);                               \
    AY = fmaf(__uint_as_float(xw & 0xFFFF0000u), nm, AY); }
  for (int c = b0; c < b3; c += 64) {
    int m = b3 - c; m = m > 64 ? 64 : m;
    u32 lo = 0, hi = 0;
    if (lane < m) {
      u64 rec = csr[(size_t)c + lane];
      lo = (u32)rec; hi = (u32)(rec >> 32);
    }
    int j1 = b1 - c; j1 = j1 < 0 ? 0 : (j1 > m ? m : j1);
    int j2 = b2 - c; j2 = j2 < 0 ? 0 : (j2 > m ? m : j2);
    int j = 0;
    for (; j + 4 <= j1; j += 4) { PAIRB(j, a0x, a0y) PAIRB(j + 2, a0x, a0y) }
    if (j < j1) { PAIRB(j, a0x, a0y) j += 2; }
    for (; j + 4 <= j2; j += 4) { PAIRB(j, a1x, a1y) PAIRB(j + 2, a1x, a1y) }
    if (j < j2) { PAIRB(j, a1x, a1y) j += 2; }
    for (; j + 4 <= m; j += 4) { PAIRB(j, a2x, a2y) PAIRB(j + 2, a2x, a2y) }
    if (j < m) { PAIRB(j, a2x, a2y) j += 2; }
  }
#undef PAIRB
  a0x += __shfl_xor(a0x, 32); a0y += __shfl_xor(a0y, 32);
  a1x += __shfl_xor(a1x, 32); a1y += __shfl_xor(a1y, 32);
  a2x += __shfl_xor(a2x, 32); a2y += __shfl_xor(a2y, 32);
  if (half == 0) {
    u32* orow = (u32*)(ACCbf + (size_t)wv * 192);
    orow[c2]      = pk2(a0x, a0y);
    orow[32 + c2] = pk2(a1x, a1y);
    orow[64 + c2] = pk2(a2x, a2y);
  }
}

// ---------------------------------------------------------------------------
// Gate GEMM: one KO=64 gate per block-group (grid = NG*391). 512 threads =
// 8 waves x 32 rows. Small LDS panel (24.6-32.8KB) + acc=32 VGPR + capped
// regalloc (launch_bounds 512,6) -> target 24 waves/CU.
//   LAYER 1: 3 gates (r,z,in), K=192 from A1.
//   LAYER 2: 4 gates (r,z: K=256 concat; in: K=192; hn: K=64 from A2).
// ---------------------------------------------------------------------------
template<int LAYER>
__global__ __launch_bounds__(512, 6) void gate_gemm(
    const u16* __restrict__ A1, const u16* __restrict__ A2,
    const u32* __restrict__ Pg, u16* __restrict__ GG, int n) {
  constexpr int KSP = (LAYER == 1) ? 6 : 8;
  constexpr int NFRAG = KSP * 4;
  __shared__ u32 bsh[NFRAG * 256];
  const int g = blockIdx.x / NBKT, blk = blockIdx.x - g * NBKT;
  int ksl = 0, ksh = 6;
  if (LAYER == 2) { ksl = (g == 3) ? 6 : 0; ksh = (g == 2) ? 6 : 8; }
  const int lane = threadIdx.x & 63, w = threadIdx.x >> 6;
  const int rr = lane & 15, kg = lane >> 4;
  const long mbase = (long)blk * 256 + w * 32;

  const u32* P = Pg + (long)g * NFRAG * 256;
#pragma unroll
  for (int i = 0; i < NFRAG / 8; ++i) {
    int c = i * 8 + w;
    __builtin_amdgcn_global_load_lds(GLBP(P + (long)c * 256 + lane * 4),
                                     LDSP(&bsh[c * 256]), 16, 0, 0);
  }
  __syncthreads();

  f32x4 acc[2][4] = {};
  for (int ks = ksl; ks < ksh; ++ks) {
    bf16x8 a0, a1;
    if (ks < 6) {
      a0 = *reinterpret_cast<const bf16x8*>(A1 + (mbase + rr) * 192 + ks * 32 + kg * 8);
      a1 = *reinterpret_cast<const bf16x8*>(A1 + (mbase + 16 + rr) * 192 + ks * 32 + kg * 8);
    } else {
      a0 = *reinterpret_cast<const bf16x8*>(A2 + (mbase + rr) * 64 + (ks - 6) * 32 + kg * 8);
      a1 = *reinterpret_cast<const bf16x8*>(A2 + (mbase + 16 + rr) * 64 + (ks - 6) * 32 + kg * 8);
    }
#pragma unroll
    for (int o = 0; o < 4; ++o) {
      bf16x8 b = *reinterpret_cast<const bf16x8*>(&bsh[((ks * 4 + o) * 64 + lane) * 4]);
      acc[0][o] = __builtin_amdgcn_mfma_f32_16x16x32_bf16(a0, b, acc[0][o], 0, 0, 0);
      acc[1][o] = __builtin_amdgcn_mfma_f32_16x16x32_bf16(a1, b, acc[1][o], 0, 0, 0);
    }
  }

  u16* Gg = GG + (long)g * ((long)NP * 64);
#pragma unroll
  for (int tl = 0; tl < 2; ++tl)
#pragma unroll
    for (int o = 0; o < 4; ++o)
#pragma unroll
      for (int q = 0; q < 4; ++q) {
        long row = mbase + tl * 16 + kg * 4 + q;
        if (row < n) Gg[row * 64 + o * 16 + rr] = f2bf(acc[tl][o][q]);
      }
}

// ---------------- GRU combine (elementwise) + optional ker-BN stats ----------
template<int USE_H, int CS>
__global__ __launch_bounds__(256) void gru_combine(
    const u16* __restrict__ GG, const u16* __restrict__ Hin, u16* __restrict__ Hout,
    const float* __restrict__ bih, const float* __restrict__ bhh,
    float* __restrict__ csum) {
  __shared__ float cs[128];
  const int t = threadIdx.x;
  if (CS) {
    for (int i = t; i < 128; i += 256) cs[i] = 0.f;
    __syncthreads();
  }
  float s[4] = {0.f, 0.f, 0.f, 0.f}, ss[4] = {0.f, 0.f, 0.f, 0.f};
  const long tot = (long)NN * 16;
  int c0 = -1;
  for (long i = (long)blockIdx.x * 256 + t; i < tot; i += (long)gridDim.x * 256) {
    long node = i >> 4;
    c0 = (int)(i & 15) * 4;  // constant per thread (stride divisible by 16)
    ushort4 vr = *reinterpret_cast<const ushort4*>(GG + node * 64 + c0);
    ushort4 vz = *reinterpret_cast<const ushort4*>(GG + (long)NP * 64 + node * 64 + c0);
    ushort4 vi = *reinterpret_cast<const ushort4*>(GG + (long)2 * NP * 64 + node * 64 + c0);
    ushort4 vh = make_ushort4(0, 0, 0, 0), hv = make_ushort4(0, 0, 0, 0);
    if (USE_H) {
      vh = *reinterpret_cast<const ushort4*>(GG + (long)3 * NP * 64 + node * 64 + c0);
      hv = *reinterpret_cast<const ushort4*>(Hin + node * 64 + c0);
    }
    u16 gr[4] = {vr.x, vr.y, vr.z, vr.w};
    u16 gz[4] = {vz.x, vz.y, vz.z, vz.w};
    u16 gi[4] = {vi.x, vi.y, vi.z, vi.w};
    u16 gh[4] = {vh.x, vh.y, vh.z, vh.w};
    u16 hl[4] = {hv.x, hv.y, hv.z, hv.w};
    u16 ov[4];
#pragma unroll
    for (int k = 0; k < 4; ++k) {
      int c = c0 + k;
      float r = sigm(bf2f(gr[k]) + bih[c] + bhh[c]);
      float z = sigm(bf2f(gz[k]) + bih[64 + c] + bhh[64 + c]);
      float h;
      if (USE_H) {
        float ng = tanhf(bf2f(gi[k]) + bih[128 + c] + r * (bf2f(gh[k]) + bhh[128 + c]));
        h = (1.f - z) * ng + z * bf2f(hl[k]);
      } else {
        float ng = tanhf(bf2f(gi[k]) + bih[128 + c] + r * bhh[128 + c]);
        h = (1.f - z) * ng;
      }
      ov[k] = f2bf(h);
      if (CS) { s[k] += h; ss[k] += h * h; }
    }
    *reinterpret_cast<ushort4*>(Hout + node * 64 + c0) = make_ushort4(ov[0], ov[1], ov[2], ov[3]);
  }
  if (CS) {
    if (c0 >= 0) {
#pragma unroll
      for (int k = 0; k < 4; ++k) {
        atomicAdd(&cs[c0 + k], s[k]);
        atomicAdd(&cs[64 + c0 + k], ss[k]);
      }
    }
    __syncthreads();
    if (t < 128) atomicAdd(&csum[t], cs[t]);
  }
}

// ---------------------------------------------------------------------------
// MFMA GEMM (r12 structure) — used for emb (AF32) and head (KO=128) only.
// ---------------------------------------------------------------------------
template<int K, int KO, int AF32, int CS, int OUTBF>
__global__ __launch_bounds__(512) void gemm_mfma(
    const void* __restrict__ Av, const u32* __restrict__ Wpk, void* __restrict__ Yv,
    float* __restrict__ csum, int n) {
  constexpr int KOT = KO / 16, KS = K / 32;
  constexpr int NFRAG = KS * KOT;
  __shared__ u32 bsh[NFRAG * 256];
  __shared__ float cs[2 * KO];
  const int lane = threadIdx.x & 63, w = threadIdx.x >> 6;
  const int rr = lane & 15, kg = lane >> 4;
  const long mbase = (long)blockIdx.x * 256 + w * 32;
  const u16* Abf = (const u16*)Av;
  const float* Af = (const float*)Av;

  bf16x8 abf[KS][2];
  float4 araw[AF32 ? KS : 1][2][2];
  if (AF32) {
#pragma unroll
    for (int ks = 0; ks < KS; ++ks)
#pragma unroll
      for (int hh = 0; hh < 2; ++hh) {
        long r = mbase + hh * 16 + rr;
        if (r > n - 1) r = n - 1;
        const float* pp = Af + r * K + ks * 32 + kg * 8;
        araw[ks][hh][0] = *(const float4*)pp;
        araw[ks][hh][1] = *(const float4*)(pp + 4);
      }
  } else {
#pragma unroll
    for (int ks = 0; ks < KS; ++ks)
#pragma unroll
      for (int hh = 0; hh < 2; ++hh)
        abf[ks][hh] = *reinterpret_cast<const bf16x8*>(
            Abf + (mbase + hh * 16 + rr) * K + ks * 32 + kg * 8);
  }

  constexpr int PASSES = NFRAG / 8;
#pragma unroll
  for (int i = 0; i < PASSES; ++i) {
    int c = i * 8 + w;
    __builtin_amdgcn_global_load_lds(GLBP(Wpk + (long)c * 256 + lane * 4),
                                     LDSP(&bsh[c * 256]), 16, 0, 0);
  }
  __syncthreads();

  if (AF32) {
#pragma unroll
    for (int ks = 0; ks < KS; ++ks)
#pragma unroll
      for (int hh = 0; hh < 2; ++hh) {
        float4 u0 = araw[ks][hh][0], u1 = araw[ks][hh][1];
        bf16x8 o_;
        o_[0] = __builtin_bit_cast(__bf16, f2bf(u0.x));
        o_[1] = __builtin_bit_cast(__bf16, f2bf(u0.y));
        o_[2] = __builtin_bit_cast(__bf16, f2bf(u0.z));
        o_[3] = __builtin_bit_cast(__bf16, f2bf(u0.w));
        o_[4] = __builtin_bit_cast(__bf16, f2bf(u1.x));
        o_[5] = __builtin_bit_cast(__bf16, f2bf(u1.y));
        o_[6] = __builtin_bit_cast(__bf16, f2bf(u1.z));
        o_[7] = __builtin_bit_cast(__bf16, f2bf(u1.w));
        abf[ks][hh] = o_;
      }
  }

  f32x4 acc[2][KOT] = {};
#pragma unroll
  for (int ks = 0; ks < KS; ++ks) {
#pragma unroll
    for (int o = 0; o < KOT; ++o) {
      bf16x8 bfr = *reinterpret_cast<const bf16x8*>(&bsh[((ks * KOT + o) * 64 + lane) * 4]);
      acc[0][o] = __builtin_amdgcn_mfma_f32_16x16x32_bf16(abf[ks][0], bfr, acc[0][o], 0, 0, 0);
      acc[1][o] = __builtin_amdgcn_mfma_f32_16x16x32_bf16(abf[ks][1], bfr, acc[1][o], 0, 0, 0);
    }
  }

  float s[KOT] = {}, ss[KOT] = {};
#pragma unroll
  for (int tl = 0; tl < 2; ++tl)
#pragma unroll
    for (int o = 0; o < KOT; ++o)
#pragma unroll
      for (int q = 0; q < 4; ++q) {
        long row = mbase + tl * 16 + kg * 4 + q;
        float vv = acc[tl][o][q];
        if (row < n) {
          long off = row * KO + o * 16 + rr;
          if (OUTBF) ((u16*)Yv)[off] = f2bf(vv);
          else       ((float*)Yv)[off] = vv;
          if (CS) { s[o] += vv; ss[o] += vv * vv; }
        }
      }
  if (CS) {
    for (int i = threadIdx.x; i < 2 * KO; i += 512) cs[i] = 0.f;
    __syncthreads();
#pragma unroll
    for (int o = 0; o < KOT; ++o) {
      int c = o * 16 + rr;
      atomicAdd(&cs[c], s[o]);
      atomicAdd(&cs[KO + c], ss[o]);
    }
    __syncthreads();
    for (int i = threadIdx.x; i < 2 * KO; i += 512) atomicAdd(&csum[i], cs[i]);
  }
}

// ---------------- BN apply with inline finalize (f32 in, bf16 out) ------------
__global__ __launch_bounds__(256) void bn_apply_bf(const float* __restrict__ X,
                                                   u16* __restrict__ Y,
                                                   const float* __restrict__ accs,
                                                   const float* __restrict__ gamma,
                                                   const float* __restrict__ beta, int relu) {
  __shared__ float scsh[128];
  int t = threadIdx.x;
  if (t < 64) {
    float mean = accs[t] * (1.f / NN);
    float var = accs[64 + t] * (1.f / NN) - mean * mean;
    float sc = gamma[t] * rsqrtf(var + EPSV);
    scsh[t] = sc;
    scsh[64 + t] = beta[t] - mean * sc;
  }
  __syncthreads();
  long i = (long)blockIdx.x * 256 + t;  // NN*16 float4s
  float4 v = reinterpret_cast<const float4*>(X)[i];
  int c = (int)((i * 4) & 63);
  v.x = fmaf(v.x, scsh[c],     scsh[64 + c]);
  v.y = fmaf(v.y, scsh[c + 1], scsh[65 + c]);
  v.z = fmaf(v.z, scsh[c + 2], scsh[66 + c]);
  v.w = fmaf(v.w, scsh[c + 3], scsh[67 + c]);
  if (relu) {
    v.x = fmaxf(v.x, 0.f); v.y = fmaxf(v.y, 0.f);
    v.z = fmaxf(v.z, 0.f); v.w = fmaxf(v.w, 0.f);
  }
  reinterpret_cast<ushort4*>(Y)[i] = make_ushort4(f2bf(v.x), f2bf(v.y), f2bf(v.z), f2bf(v.w));
}

// ---------------- final head: inline BN finalize + ReLU + tiny GEMM -----------
template<int KO>
__global__ __launch_bounds__(256) void headfin_bn(const u16* __restrict__ Z,
                                                  const float* __restrict__ asum,
                                                  const float* __restrict__ asq,
                                                  const float* __restrict__ gamma,
                                                  const float* __restrict__ beta,
                                                  const float* __restrict__ W2,
                                                  const float* __restrict__ b2,
                                                  float* __restrict__ out, int n) {
  __shared__ float ws[KO * 64];
  __shared__ float scsh[128];
  int t = threadIdx.x;
  if (t < 64) {
    float mean = asum[t] * (1.f / NN);
    float var = asq[t] * (1.f / NN) - mean * mean;
    float sc = gamma[t] * rsqrtf(var + EPSV);
    scsh[t] = sc;
    scsh[64 + t] = beta[t] - mean * sc;
  }
  for (int i = t; i < KO * 64; i += 256) ws[i] = W2[i];
  __syncthreads();
  long node = (long)blockIdx.x * 256 + t;
  if (node >= n) return;
  const u16* zr = Z + node * 128;
  float x[64];
#pragma unroll
  for (int i = 0; i < 16; ++i) {
    ushort4 z4 = reinterpret_cast<const ushort4*>(zr)[i];
    int c = i * 4;
    x[c]     = fmaxf(fmaf(bf2f(z4.x), scsh[c],     scsh[64 + c]), 0.f);
    x[c + 1] = fmaxf(fmaf(bf2f(z4.y), scsh[c + 1], scsh[65 + c]), 0.f);
    x[c + 2] = fmaxf(fmaf(bf2f(z4.z), scsh[c + 2], scsh[66 + c]), 0.f);
    x[c + 3] = fmaxf(fmaf(bf2f(z4.w), scsh[c + 3], scsh[67 + c]), 0.f);
  }
#pragma unroll
  for (int o = 0; o < KO; ++o) {
    float a = b2[o];
#pragma unroll
    for (int d = 0; d < 64; ++d) a = fmaf(x[d], ws[o * 64 + d], a);
    out[node * KO + o] = a;
  }
}

extern "C" void kernel_launch(void* const* d_in, const int* in_sizes, int n_in,
                              void* d_out, int out_size, void* d_ws, size_t ws_size,
                              hipStream_t stream) {
  const float* v     = (const float*)d_in[0];
  const int*   src   = (const int*)d_in[1];
  const int*   dst   = (const int*)d_in[2];
  const int*   rt    = (const int*)d_in[3];
  const float* norm  = (const float*)d_in[4];
  const float* emb_W = (const float*)d_in[5];
  const float* emb_g  = (const float*)d_in[7];
  const float* emb_be = (const float*)d_in[8];
  const float* rel_w  = (const float*)d_in[9];
  const float* Wih    = (const float*)d_in[10];
  const float* Whh    = (const float*)d_in[11];
  const float* bih    = (const float*)d_in[12];
  const float* bhh    = (const float*)d_in[13];
  const float* ker_g  = (const float*)d_in[14];
  const float* aW1    = (const float*)d_in[16];
  const float* a_g  = (const float*)d_in[18];
  const float* a_be = (const float*)d_in[19];
  const float* aW2  = (const float*)d_in[20];
  const float* ab2  = (const float*)d_in[21];
  const float* bW1  = (const float*)d_in[22];
  const float* b_g  = (const float*)d_in[24];
  const float* b_be = (const float*)d_in[25];
  const float* bW2  = (const float*)d_in[26];
  const float* bb2  = (const float*)d_in[27];
  float* out = (float*)d_out;

  // ---- workspace carve-up (GG aliases dead Z/X2/REG region) ----
  char* p = (char*)d_ws;
  auto nxt = [&](size_t bytes) -> char* {
    char* r = p; p += (bytes + 255) & ~(size_t)255; return r;
  };
  int*   GCNT = (int*)nxt(512 * 4);
  float* ACCs = (float*)nxt(512 * 4);
  char*  GGZ  = nxt((size_t)NP * 64 * 4 + (size_t)NP * 64 * 2 + (size_t)NBKT * CAP * 8);
  float* Z    = (float*)GGZ;                                  // emb f32 pre-acts
  u16*   X2   = (u16*)(GGZ + (size_t)NP * 64 * 4);            // h0 bf16
  u64*   REG  = (u64*)(GGZ + (size_t)NP * 64 * 4 + (size_t)NP * 64 * 2);
  u16*   GG   = (u16*)GGZ;                                    // [4][NP,64] gate bufs (late)
  u16*   X1   = (u16*)nxt((size_t)NP * 64 * 2);               // h bf16
  u16*   ACCB = (u16*)nxt((size_t)NP * 192 * 2);              // gathered rel-sums / head pre
  u64*   CSR  = (u64*)nxt((size_t)(NE + NBKT * 768 + 64) * 8);
  int*   BBAS = (int*)nxt(512 * 4);
  int*   ROWPR = (int*)nxt((size_t)(NP + 8) * 4 * 4);
  u32*   PWem = (u32*)nxt(2048 * 4);
  u32*   PG1  = (u32*)nxt(18432 * 4);
  u32*   PG2  = (u32*)nxt(32768 * 4);
  u32*   PWab = (u32*)nxt(4096 * 4);
  float* WROW = (float*)nxt(147456);

  hipMemsetAsync(GCNT, 0, 1024 * 4, stream);

  // setup + CSR build
  setupA<<<152, 256, 0, stream>>>(rel_w, Wih, emb_W, WROW, PWem);
  countplace<<<782, 256, 0, stream>>>(src, dst, rt, norm, GCNT, REG);
  bucketscan<<<1, 512, 0, stream>>>(GCNT, BBAS);
  localsort<<<NBKT, 256, 0, stream>>>(GCNT, BBAS, REG, CSR, ROWPR);
  pack_g1<<<72, 256, 0, stream>>>(WROW, PG1);
  pack_g2<<<128, 256, 0, stream>>>(WROW, Whh, PG2);

  // embedding: Z = v @ emb_W^T (fused colsum); X2 = bf16(relu(BN(Z)))
  gemm_mfma<64, 64, 1, 1, 0><<<391, 512, 0, stream>>>(v, PWem, Z, ACCs + 0, NN);
  bn_apply_bf<<<6250, 256, 0, stream>>>(Z, X2, ACCs + 0, emb_g, emb_be, 1);

  // layer 1: gather -> 3 gate GEMMs (one dispatch) -> combine -> X1 = h1
  csr_gather<<<25000, 256, 0, stream>>>(ROWPR, CSR, X2, ACCB);
  gate_gemm<1><<<3 * NBKT, 512, 0, stream>>>(ACCB, (const u16*)nullptr, PG1, GG, NN);
  gru_combine<0, 0><<<6250, 256, 0, stream>>>(GG, (const u16*)nullptr, X1, bih, bhh, nullptr);

  // layer 2: gather -> 4 gate GEMMs (K-concat absorbs Whh) -> combine(+ker stats)
  csr_gather<<<25000, 256, 0, stream>>>(ROWPR, CSR, X1, ACCB);
  gate_gemm<2><<<4 * NBKT, 512, 0, stream>>>(ACCB, X1, PG2, GG, NN);
  gru_combine<1, 1><<<416, 256, 0, stream>>>(GG, X1, X1, bih, bhh, ACCs + 128);

  // heads: fold ker-BN scale into both W1s, one KO=128 GEMM + per-head finish
  fold_pack<<<16, 256, 0, stream>>>(aW1, bW1, ACCs + 128, ker_g, PWab);
  gemm_mfma<64, 128, 0, 1, 1><<<391, 512, 0, stream>>>(X1, PWab, ACCB, ACCs + 256, NN);
  headfin_bn<2><<<391, 256, 0, stream>>>((const u16*)ACCB, ACCs + 256, ACCs + 384,
                                         a_g, a_be, aW2, ab2, out, NN);
  headfin_bn<21><<<391, 256, 0, stream>>>((const u16*)ACCB + 64, ACCs + 320, ACCs + 448,
                                          b_g, b_be, bW2, bb2, out + (long)NN * 2, NN);
}

// Round 14
// 372.257 us; speedup vs baseline: 1.1393x; 1.1393x over previous
//
#include <hip/hip_runtime.h>

#define NN 100000
#define NE 1600000
#define NP 100096   // 391 * 256 rows, GEMM tile padding
#define NBKT 391    // ceil(NN/256) coarse buckets
#define CAP 6144    // padded region capacity per bucket
#define EPSV 1e-5f

typedef unsigned int u32;
typedef unsigned short u16;
typedef unsigned long long u64;
typedef __bf16 bf16x8 __attribute__((ext_vector_type(8)));
typedef float f32x4 __attribute__((ext_vector_type(4)));

#define GLBP(x) ((const __attribute__((address_space(1))) u32*)(x))
#define LDSP(x) ((__attribute__((address_space(3))) u32*)(x))

__device__ __forceinline__ u16 f2bf(float f) {
  u32 x = __float_as_uint(f);
  return (u16)((x + 0x7FFFu + ((x >> 16) & 1u)) >> 16);  // RNE
}
__device__ __forceinline__ float bf2f(u16 h) { return __uint_as_float(((u32)h) << 16); }
__device__ __forceinline__ u32 pk2(float a, float b) {
  return (u32)f2bf(a) | ((u32)f2bf(b) << 16);
}

// ---------------- setup A: wfuse (blocks 0..143) | pack emb (144..151) | pack Whh (152..175)
__device__ __forceinline__ void pack_one(const float* W, u32* out, int K, int KOT, int i) {
  int q = i & 3, lane = (i >> 2) & 63, f = i >> 8;
  int ks = f / KOT, ot = f - ks * KOT;
  int o = ot * 16 + (lane & 15);
  int k = ks * 32 + (lane >> 4) * 8 + q * 2;
  out[i] = pk2(W[o * K + k], W[o * K + k + 1]);
}

__global__ void setupA(const float* __restrict__ relw, const float* __restrict__ Wih,
                       const float* __restrict__ embW, const float* __restrict__ Whh,
                       float* __restrict__ Wrow, u32* __restrict__ PWem, u32* __restrict__ PWhh) {
  int b = blockIdx.x;
  if (b < 144) {
    int t = b * 256 + threadIdx.x;
    if (t >= 192 * 192) return;
    int kg = t / 192, j = t % 192;
    const float* a = relw + (j >> 6) * 4096 + (j & 63) * 64;
    const float* w = Wih + kg * 64;
    float s = 0.f;
#pragma unroll
    for (int k = 0; k < 64; ++k) s += a[k] * w[k];
    Wrow[kg * 192 + j] = s;
  } else if (b < 152) {
    pack_one(embW, PWem, 64, 4, (b - 144) * 256 + threadIdx.x);
  } else {
    pack_one(Whh, PWhh, 64, 12, (b - 152) * 256 + threadIdx.x);
  }
}

__global__ void pack_wf(const float* __restrict__ Wrow, u32* __restrict__ PWf) {
  pack_one(Wrow, PWf, 192, 12, blockIdx.x * 256 + threadIdx.x);  // 72 blocks
}

// pack BOTH head weights (128 rows) folded with inline ker-BN scale
__global__ void fold_pack(const float* __restrict__ Wa, const float* __restrict__ Wb,
                          const float* __restrict__ kacc, const float* __restrict__ kg,
                          u32* __restrict__ P) {
  int i = blockIdx.x * 256 + threadIdx.x;  // 4096 = KS(2)*KOT(8)*256
  int q = i & 3, lane = (i >> 2) & 63, f = i >> 8;
  int ks = f >> 3, ot = f & 7;
  int o = ot * 16 + (lane & 15);            // 0..127
  int k = ks * 32 + (lane >> 4) * 8 + q * 2;
  const float* W = (o < 64) ? (Wa + o * 64) : (Wb + (o - 64) * 64);
  const float inv = 1.f / NN;
  float m0 = kacc[k] * inv;
  float s0 = kg[k] * rsqrtf(kacc[64 + k] * inv - m0 * m0 + EPSV);
  float m1 = kacc[k + 1] * inv;
  float s1 = kg[k + 1] * rsqrtf(kacc[64 + k + 1] * inv - m1 * m1 + EPSV);
  P[i] = pk2(W[k] * s0, W[k + 1] * s1);
}

// ---------------------------------------------------------------------------
// Hierarchical CSR build.
// record: low u32 = src(0..19) | rel(20..21) | dst&255(22..29); high u32 = norm
// ---------------------------------------------------------------------------
__global__ __launch_bounds__(256) void countplace(const int* __restrict__ src,
                                                  const int* __restrict__ dst,
                                                  const int* __restrict__ rt,
                                                  const float* __restrict__ nrm,
                                                  int* __restrict__ gcnt,
                                                  u64* __restrict__ region) {
  __shared__ u32 hist[NBKT], gbase[NBKT];
  const int t = threadIdx.x;
  for (int i = t; i < NBKT; i += 256) hist[i] = 0;
  __syncthreads();
  const int e0 = blockIdx.x * 2048 + t;
  u32 rlo[8], rhi[8], lrank[8];
  int bkt[8];
#pragma unroll
  for (int i = 0; i < 8; ++i) {
    int e = e0 + i * 256;
    bkt[i] = -1;
    if (e < NE) {
      int d = dst[e];
      int b = d >> 8;
      bkt[i] = b;
      lrank[i] = atomicAdd(&hist[b], 1u);
      rlo[i] = (u32)src[e] | ((u32)rt[e] << 20) | ((u32)(d & 255) << 22);
      rhi[i] = __float_as_uint(nrm[e]);
    }
  }
  __syncthreads();
  for (int i = t; i < NBKT; i += 256) {
    u32 h = hist[i];
    gbase[i] = h ? (u32)atomicAdd(&gcnt[i], (int)h) : 0u;
  }
  __syncthreads();
#pragma unroll
  for (int i = 0; i < 8; ++i) {
    if (bkt[i] >= 0) {
      u32 pos = gbase[bkt[i]] + lrank[i];
      if (pos < CAP)
        region[(size_t)bkt[i] * CAP + pos] = (u64)rlo[i] | ((u64)rhi[i] << 32);
    }
  }
}

// exclusive prefix over PADDED bucket sizes (gcnt + 768 slack for even-padding)
__global__ __launch_bounds__(512) void bucketscan(const int* __restrict__ gcnt,
                                                  int* __restrict__ bbase) {
  int t = threadIdx.x;
  int v = (t < NBKT) ? (gcnt[t] + 768) : 0;
  __shared__ int sh[512];
  sh[t] = v;
  __syncthreads();
#pragma unroll
  for (int off = 1; off < 512; off <<= 1) {
    int u = (t >= off) ? sh[t - off] : 0;
    __syncthreads();
    sh[t] += u;
    __syncthreads();
  }
  if (t < NBKT) bbase[t] = sh[t] - v;  // exclusive
}

// 1024-bin counting sort per bucket, each (node,rel) segment padded to EVEN
// length via zero-norm dummies. rowpr[4*node+r] = padded boundaries.
__global__ __launch_bounds__(256) void localsort(const int* __restrict__ gcnt,
                                                 const int* __restrict__ bbase,
                                                 const u64* __restrict__ region,
                                                 u64* __restrict__ csr,
                                                 int* __restrict__ rowpr) {
  const int b = blockIdx.x, t = threadIdx.x;
  int n = gcnt[b];
  if (n > CAP) n = CAP;
  const int base = bbase[b];
  __shared__ u32 hist[1024], sc[256];
#pragma unroll
  for (int i = 0; i < 4; ++i) hist[t + 256 * i] = 0;
  __syncthreads();
  for (int i = t; i < n; i += 256)
    atomicAdd(&hist[(u32)(region[(size_t)b * CAP + i] >> 20) & 1023u], 1u);
  __syncthreads();
  u32 a0 = hist[4 * t], a1 = hist[4 * t + 1], a2 = hist[4 * t + 2];
  u32 p0 = (a0 + 1) & ~1u, p1 = (a1 + 1) & ~1u, p2 = (a2 + 1) & ~1u;
  u32 part = p0 + p1 + p2;
  sc[t] = part;
  __syncthreads();
#pragma unroll
  for (int off = 1; off < 256; off <<= 1) {
    u32 u = (t >= off) ? sc[t - off] : 0;
    __syncthreads();
    sc[t] += u;
    __syncthreads();
  }
  u32 ex = sc[t] - part;
  int node = b * 256 + t;
  rowpr[4 * node + 0] = base + (int)ex;
  rowpr[4 * node + 1] = base + (int)(ex + p0);
  rowpr[4 * node + 2] = base + (int)(ex + p0 + p1);
  rowpr[4 * node + 3] = base + (int)(ex + p0 + p1 + p2);
  __syncthreads();
  hist[4 * t + 0] = ex;
  hist[4 * t + 1] = ex + p0;
  hist[4 * t + 2] = ex + p0 + p1;
  __syncthreads();
  for (int i = t; i < n; i += 256) {
    u64 rec = region[(size_t)b * CAP + i];
    u32 pos = atomicAdd(&hist[(u32)(rec >> 20) & 1023u], 1u);
    csr[(size_t)base + pos] = rec;
  }
  __syncthreads();
  if (a0 & 1) csr[(size_t)base + ex + a0] = 0ull;
  if (a1 & 1) csr[(size_t)base + ex + p0 + a1] = 0ull;
  if (a2 & 1) csr[(size_t)base + ex + p0 + p1 + a2] = 0ull;
}

// ---------------- CSR gather: wave per node; OUTPUT IN MFMA FRAGMENT LAYOUT.
// frag u32 idx = (((tile*8+w)*6+ks)*2+hh)*256 + (kg*16+rr)*4 + j2
// where node = tile*256 + w*32 + hh*16 + rr, feature f = ks*32+kg*8+2*j2.
__global__ __launch_bounds__(256) void csr_gather(const int* __restrict__ rowpr,
                                                  const u64* __restrict__ csr,
                                                  const u16* __restrict__ Xbf,
                                                  u32* __restrict__ AFRAG) {
  int wv = blockIdx.x * 4 + (threadIdx.x >> 6);
  int lane = threadIdx.x & 63;
  if (wv >= NN) return;
  const int half = lane >> 5, c2 = lane & 31;
  int4 rp = *reinterpret_cast<const int4*>(rowpr + 4 * wv);
  const int b0 = __builtin_amdgcn_readfirstlane(rp.x);
  const int b1 = __builtin_amdgcn_readfirstlane(rp.y);
  const int b2 = __builtin_amdgcn_readfirstlane(rp.z);
  const int b3 = __builtin_amdgcn_readfirstlane(rp.w);
  const u32* X4 = (const u32*)Xbf;
  float a0x = 0.f, a0y = 0.f, a1x = 0.f, a1y = 0.f, a2x = 0.f, a2y = 0.f;
#define PAIRB(J, AX, AY)                                                        \
  { u32 sA = (u32)__builtin_amdgcn_readlane((int)lo, (J));                      \
    u32 sB = (u32)__builtin_amdgcn_readlane((int)lo, (J) + 1);                  \
    u32 nA = (u32)__builtin_amdgcn_readlane((int)hi, (J));                      \
    u32 nB = (u32)__builtin_amdgcn_readlane((int)hi, (J) + 1);                  \
    u32 srp = half ? sB : sA;                                                   \
    float nm = __uint_as_float(half ? nB : nA);                                 \
    u32 xw = X4[((srp & 0xFFFFFu) << 5) | (u32)c2];                             \
    AX = fmaf(__uint_as_float(xw << 16), nm, AX);                               \
    AY = fmaf(__uint_as_float(xw & 0xFFFF0000u), nm, AY); }
  for (int c = b0; c < b3; c += 64) {
    int m = b3 - c; m = m > 64 ? 64 : m;
    u32 lo = 0, hi = 0;
    if (lane < m) {
      u64 rec = csr[(size_t)c + lane];
      lo = (u32)rec; hi = (u32)(rec >> 32);
    }
    int j1 = b1 - c; j1 = j1 < 0 ? 0 : (j1 > m ? m : j1);
    int j2 = b2 - c; j2 = j2 < 0 ? 0 : (j2 > m ? m : j2);
    int j = 0;
    for (; j + 4 <= j1; j += 4) { PAIRB(j, a0x, a0y) PAIRB(j + 2, a0x, a0y) }
    if (j < j1) { PAIRB(j, a0x, a0y) j += 2; }
    for (; j + 4 <= j2; j += 4) { PAIRB(j, a1x, a1y) PAIRB(j + 2, a1x, a1y) }
    if (j < j2) { PAIRB(j, a1x, a1y) j += 2; }
    for (; j + 4 <= m; j += 4) { PAIRB(j, a2x, a2y) PAIRB(j + 2, a2x, a2y) }
    if (j < m) { PAIRB(j, a2x, a2y) j += 2; }
  }
#undef PAIRB
  a0x += __shfl_xor(a0x, 32); a0y += __shfl_xor(a0y, 32);
  a1x += __shfl_xor(a1x, 32); a1y += __shfl_xor(a1y, 32);
  a2x += __shfl_xor(a2x, 32); a2y += __shfl_xor(a2y, 32);
  if (half == 0) {
    const int tile = wv >> 8, rowit = wv & 255;
    const int w8 = rowit >> 5, hh = (rowit >> 4) & 1, rrn = rowit & 15;
    const long fb = ((long)tile * 8 + w8) * 6;
#define FWR(R, AX, AY)                                                          \
    { int f0 = (R) * 64 + 2 * c2;                                               \
      int ks = f0 >> 5, r5 = f0 & 31;                                           \
      int kgx = r5 >> 3, jj = (r5 & 7) >> 1;                                    \
      AFRAG[((fb + ks) * 2 + hh) * 256 + (kgx * 16 + rrn) * 4 + jj] = pk2(AX, AY); }
    FWR(0, a0x, a0y)
    FWR(1, a1x, a1y)
    FWR(2, a2x, a2y)
#undef FWR
  }
}

// ---------------------------------------------------------------------------
// MFMA GEMM: 512 threads = 8 waves, 32 rows/wave, 256 rows/block. Whole-B in
// LDS staged once, single barrier; A loads issued upfront.
//   AFR: A is in fragment layout (wave-contiguous 1KB bursts).
//   AF32: A is f32 row-major (row-clamped); GRU: 0/1/2; CS: stats
// ---------------------------------------------------------------------------
template<int K, int KO, int AFR, int AF32, int GRU, int CS, int OUTBF>
__global__ __launch_bounds__(512) void gemm_mfma(
    const void* __restrict__ Av, const u32* __restrict__ Wpk, void* __restrict__ Yv,
    const float* __restrict__ bih, const float* __restrict__ bhh,
    const u16* __restrict__ G2B, const u16* __restrict__ Hv,
    float* __restrict__ csum, int n) {
  constexpr int KOT = KO / 16, KS = K / 32;
  constexpr int NFRAG = KS * KOT;
  __shared__ u32 bsh[NFRAG * 256];
  __shared__ float cs[2 * KO];
  const int lane = threadIdx.x & 63, w = threadIdx.x >> 6;  // w 0..7
  const int rr = lane & 15, kg = lane >> 4;
  const long mbase = (long)blockIdx.x * 256 + w * 32;
  const u16* Abf = (const u16*)Av;
  const float* Af = (const float*)Av;

  // ---- issue ALL A loads upfront ----
  bf16x8 abf[KS][2];
  float4 araw[AF32 ? KS : 1][2][2];
  if (AFR) {
    const long fb = ((long)blockIdx.x * 8 + w) * KS;
#pragma unroll
    for (int ks = 0; ks < KS; ++ks)
#pragma unroll
      for (int hh = 0; hh < 2; ++hh)
        abf[ks][hh] = *reinterpret_cast<const bf16x8*>(
            Abf + ((fb + ks) * 2 + hh) * 512 + lane * 8);
  } else if (AF32) {
#pragma unroll
    for (int ks = 0; ks < KS; ++ks)
#pragma unroll
      for (int hh = 0; hh < 2; ++hh) {
        long r = mbase + hh * 16 + rr;
        if (r > n - 1) r = n - 1;
        const float* pp = Af + r * K + ks * 32 + kg * 8;
        araw[ks][hh][0] = *(const float4*)pp;
        araw[ks][hh][1] = *(const float4*)(pp + 4);
      }
  } else {
#pragma unroll
    for (int ks = 0; ks < KS; ++ks)
#pragma unroll
      for (int hh = 0; hh < 2; ++hh)
        abf[ks][hh] = *reinterpret_cast<const bf16x8*>(
            Abf + (mbase + hh * 16 + rr) * K + ks * 32 + kg * 8);
  }

  // ---- stage whole B panel (8 waves cooperate) ----
  constexpr int PASSES = NFRAG / 8;
#pragma unroll
  for (int i = 0; i < PASSES; ++i) {
    int c = i * 8 + w;
    __builtin_amdgcn_global_load_lds(GLBP(Wpk + (long)c * 256 + lane * 4),
                                     LDSP(&bsh[c * 256]), 16, 0, 0);
  }
  __syncthreads();  // drains ALL outstanding loads (A + B stage)

  if (AF32) {
#pragma unroll
    for (int ks = 0; ks < KS; ++ks)
#pragma unroll
      for (int hh = 0; hh < 2; ++hh) {
        float4 u0 = araw[ks][hh][0], u1 = araw[ks][hh][1];
        bf16x8 o_;
        o_[0] = __builtin_bit_cast(__bf16, f2bf(u0.x));
        o_[1] = __builtin_bit_cast(__bf16, f2bf(u0.y));
        o_[2] = __builtin_bit_cast(__bf16, f2bf(u0.z));
        o_[3] = __builtin_bit_cast(__bf16, f2bf(u0.w));
        o_[4] = __builtin_bit_cast(__bf16, f2bf(u1.x));
        o_[5] = __builtin_bit_cast(__bf16, f2bf(u1.y));
        o_[6] = __builtin_bit_cast(__bf16, f2bf(u1.z));
        o_[7] = __builtin_bit_cast(__bf16, f2bf(u1.w));
        abf[ks][hh] = o_;
      }
  }

  f32x4 acc[2][KOT] = {};
#pragma unroll
  for (int ks = 0; ks < KS; ++ks) {
#pragma unroll
    for (int o = 0; o < KOT; ++o) {
      bf16x8 bfr = *reinterpret_cast<const bf16x8*>(&bsh[((ks * KOT + o) * 64 + lane) * 4]);
      acc[0][o] = __builtin_amdgcn_mfma_f32_16x16x32_bf16(abf[ks][0], bfr, acc[0][o], 0, 0, 0);
      acc[1][o] = __builtin_amdgcn_mfma_f32_16x16x32_bf16(abf[ks][1], bfr, acc[1][o], 0, 0, 0);
    }
  }

  float s[KOT] = {}, ss[KOT] = {};
  if (GRU == 0) {
#pragma unroll
    for (int tl = 0; tl < 2; ++tl)
#pragma unroll
      for (int o = 0; o < KOT; ++o)
#pragma unroll
        for (int q = 0; q < 4; ++q) {
          long row = mbase + tl * 16 + kg * 4 + q;
          float vv = acc[tl][o][q];
          if (row < n) {
            long off = row * KO + o * 16 + rr;
            if (OUTBF) ((u16*)Yv)[off] = f2bf(vv);
            else       ((float*)Yv)[off] = vv;
            if (CS) { s[o] += vv; ss[o] += vv * vv; }
          }
        }
  } else {
    float bi[12], bh_[12];
#pragma unroll
    for (int g = 0; g < 3; ++g)
#pragma unroll
      for (int o = 0; o < 4; ++o) {
        bi[g * 4 + o] = bih[g * 64 + o * 16 + rr];
        bh_[g * 4 + o] = bhh[g * 64 + o * 16 + rr];
      }
#pragma unroll
    for (int tl = 0; tl < 2; ++tl)
#pragma unroll
      for (int o = 0; o < 4; ++o) {
        int c = o * 16 + rr;
#pragma unroll
        for (int q = 0; q < 4; ++q) {
          long row = mbase + tl * 16 + kg * 4 + q;
          float ir = acc[tl][o][q] + bi[o];
          float iz = acc[tl][o + 4][q] + bi[4 + o];
          float in_ = acc[tl][o + 8][q] + bi[8 + o];
          float hr = bh_[o], hz = bh_[4 + o], hn = bh_[8 + o], hv = 0.f;
          if (GRU == 2) {
            const u16* g2 = G2B + row * 192;
            hr += bf2f(g2[c]); hz += bf2f(g2[64 + c]); hn += bf2f(g2[128 + c]);
            hv = bf2f(Hv[row * 64 + c]);
          }
          float rg = 1.f / (1.f + __expf(-(ir + hr)));
          float zg = 1.f / (1.f + __expf(-(iz + hz)));
          float ng = tanhf(in_ + rg * hn);
          float h = (1.f - zg) * ng + (GRU == 2 ? zg * hv : 0.f);
          if (row < n) {
            ((u16*)Yv)[row * 64 + c] = f2bf(h);
            if (CS) { s[o] += h; ss[o] += h * h; }
          }
        }
      }
  }
  if (CS) {
    constexpr int LIM = (GRU == 0) ? 2 * KO : 128;
    constexpr int CKO = (GRU == 0) ? KO : 64;
    constexpr int OL = (GRU == 0) ? KOT : 4;
    for (int i = threadIdx.x; i < LIM; i += 512) cs[i] = 0.f;
    __syncthreads();
#pragma unroll
    for (int o = 0; o < OL; ++o) {
      int c = o * 16 + rr;
      atomicAdd(&cs[c], s[o]);
      atomicAdd(&cs[CKO + c], ss[o]);
    }
    __syncthreads();
    for (int i = threadIdx.x; i < LIM; i += 512) atomicAdd(&csum[i], cs[i]);
  }
}

// ---------------- BN apply with inline finalize (f32 in, bf16 out) ------------
__global__ __launch_bounds__(256) void bn_apply_bf(const float* __restrict__ X,
                                                   u16* __restrict__ Y,
                                                   const float* __restrict__ accs,
                                                   const float* __restrict__ gamma,
                                                   const float* __restrict__ beta, int relu) {
  __shared__ float scsh[128];
  int t = threadIdx.x;
  if (t < 64) {
    float mean = accs[t] * (1.f / NN);
    float var = accs[64 + t] * (1.f / NN) - mean * mean;
    float sc = gamma[t] * rsqrtf(var + EPSV);
    scsh[t] = sc;
    scsh[64 + t] = beta[t] - mean * sc;
  }
  __syncthreads();
  long i = (long)blockIdx.x * 256 + t;  // NN*16 float4s
  float4 v = reinterpret_cast<const float4*>(X)[i];
  int c = (int)((i * 4) & 63);
  v.x = fmaf(v.x, scsh[c],     scsh[64 + c]);
  v.y = fmaf(v.y, scsh[c + 1], scsh[65 + c]);
  v.z = fmaf(v.z, scsh[c + 2], scsh[66 + c]);
  v.w = fmaf(v.w, scsh[c + 3], scsh[67 + c]);
  if (relu) {
    v.x = fmaxf(v.x, 0.f); v.y = fmaxf(v.y, 0.f);
    v.z = fmaxf(v.z, 0.f); v.w = fmaxf(v.w, 0.f);
  }
  reinterpret_cast<ushort4*>(Y)[i] = make_ushort4(f2bf(v.x), f2bf(v.y), f2bf(v.z), f2bf(v.w));
}

// ---------------- final head: inline BN finalize + ReLU + tiny GEMM -----------
template<int KO>
__global__ __launch_bounds__(256) void headfin_bn(const u16* __restrict__ Z,
                                                  const float* __restrict__ asum,
                                                  const float* __restrict__ asq,
                                                  const float* __restrict__ gamma,
                                                  const float* __restrict__ beta,
                                                  const float* __restrict__ W2,
                                                  const float* __restrict__ b2,
                                                  float* __restrict__ out, int n) {
  __shared__ float ws[KO * 64];
  __shared__ float scsh[128];
  int t = threadIdx.x;
  if (t < 64) {
    float mean = asum[t] * (1.f / NN);
    float var = asq[t] * (1.f / NN) - mean * mean;
    float sc = gamma[t] * rsqrtf(var + EPSV);
    scsh[t] = sc;
    scsh[64 + t] = beta[t] - mean * sc;
  }
  for (int i = t; i < KO * 64; i += 256) ws[i] = W2[i];
  __syncthreads();
  long node = (long)blockIdx.x * 256 + t;
  if (node >= n) return;
  const u16* zr = Z + node * 128;
  float x[64];
#pragma unroll
  for (int i = 0; i < 16; ++i) {
    ushort4 z4 = reinterpret_cast<const ushort4*>(zr)[i];
    int c = i * 4;
    x[c]     = fmaxf(fmaf(bf2f(z4.x), scsh[c],     scsh[64 + c]), 0.f);
    x[c + 1] = fmaxf(fmaf(bf2f(z4.y), scsh[c + 1], scsh[65 + c]), 0.f);
    x[c + 2] = fmaxf(fmaf(bf2f(z4.z), scsh[c + 2], scsh[66 + c]), 0.f);
    x[c + 3] = fmaxf(fmaf(bf2f(z4.w), scsh[c + 3], scsh[67 + c]), 0.f);
  }
#pragma unroll
  for (int o = 0; o < KO; ++o) {
    float a = b2[o];
#pragma unroll
    for (int d = 0; d < 64; ++d) a = fmaf(x[d], ws[o * 64 + d], a);
    out[node * KO + o] = a;
  }
}

extern "C" void kernel_launch(void* const* d_in, const int* in_sizes, int n_in,
                              void* d_out, int out_size, void* d_ws, size_t ws_size,
                              hipStream_t stream) {
  const float* v     = (const float*)d_in[0];
  const int*   src   = (const int*)d_in[1];
  const int*   dst   = (const int*)d_in[2];
  const int*   rt    = (const int*)d_in[3];
  const float* norm  = (const float*)d_in[4];
  const float* emb_W = (const float*)d_in[5];
  const float* emb_g  = (const float*)d_in[7];
  const float* emb_be = (const float*)d_in[8];
  const float* rel_w  = (const float*)d_in[9];
  const float* Wih    = (const float*)d_in[10];
  const float* Whh    = (const float*)d_in[11];
  const float* bih    = (const float*)d_in[12];
  const float* bhh    = (const float*)d_in[13];
  const float* ker_g  = (const float*)d_in[14];
  const float* aW1    = (const float*)d_in[16];
  const float* a_g  = (const float*)d_in[18];
  const float* a_be = (const float*)d_in[19];
  const float* aW2  = (const float*)d_in[20];
  const float* ab2  = (const float*)d_in[21];
  const float* bW1  = (const float*)d_in[22];
  const float* b_g  = (const float*)d_in[24];
  const float* b_be = (const float*)d_in[25];
  const float* bW2  = (const float*)d_in[26];
  const float* bb2  = (const float*)d_in[27];
  float* out = (float*)d_out;

  // ---- workspace carve-up ----
  char* p = (char*)d_ws;
  auto nxt = [&](size_t bytes) -> char* {
    char* r = p; p += (bytes + 255) & ~(size_t)255; return r;
  };
  int*   GCNT = (int*)nxt(512 * 4);                 // bucket counts (memset w/ ACCs)
  float* ACCs = (float*)nxt(512 * 4);               // raw BN stats: emb|ker|heads
  float* Z    = (float*)nxt((size_t)NP * 64 * 4);   // f32 emb pre-acts
  u16*   X1   = (u16*)nxt((size_t)NP * 64 * 2);     // h (bf16)
  u16*   X2   = (u16*)nxt((size_t)NP * 64 * 2);     // h0 (bf16)
  u16*   ACCB = (u16*)nxt((size_t)NP * 192 * 2);    // gathered rel-sums (FRAGMENT layout) / head pre
  u16*   G2B  = (u16*)nxt((size_t)NP * 192 * 2);    // h @ Whh^T
  u64*   REG  = (u64*)nxt((size_t)NBKT * CAP * 8);  // padded bucket regions
  u64*   CSR  = (u64*)nxt((size_t)(NE + NBKT * 768 + 64) * 8);  // even-padded CSR
  int*   BBAS = (int*)nxt(512 * 4);
  int*   ROWPR = (int*)nxt((size_t)(NP + 8) * 4 * 4); // per-(node,rel) padded bounds
  u32*   PWf  = (u32*)nxt(18432 * 4);
  u32*   PWem = (u32*)nxt(2048 * 4);
  u32*   PWhh = (u32*)nxt(6144 * 4);
  u32*   PWab = (u32*)nxt(4096 * 4);
  float* WROW = (float*)nxt(147456);

  hipMemsetAsync(GCNT, 0, 1024 * 4, stream);  // GCNT + ACCs contiguous

  // setup + hierarchical rel-sorted even-padded CSR build
  setupA<<<176, 256, 0, stream>>>(rel_w, Wih, emb_W, Whh, WROW, PWem, PWhh);
  countplace<<<782, 256, 0, stream>>>(src, dst, rt, norm, GCNT, REG);
  bucketscan<<<1, 512, 0, stream>>>(GCNT, BBAS);
  localsort<<<NBKT, 256, 0, stream>>>(GCNT, BBAS, REG, CSR, ROWPR);
  pack_wf<<<72, 256, 0, stream>>>(WROW, PWf);

  // embedding: Z = v @ emb_W^T (fused colsum); X2 = bf16(relu(BN(Z)))
  gemm_mfma<64, 64, 0, 1, 0, 1, 0><<<391, 512, 0, stream>>>(v, PWem, Z, nullptr, nullptr,
                                                            nullptr, nullptr, ACCs + 0, NN);
  bn_apply_bf<<<6250, 256, 0, stream>>>(Z, X2, ACCs + 0, emb_g, emb_be, 1);

  // layer 1 (h==0): gather (frag out) -> fused GEMM+GRU (frag A) -> X1 = h1
  csr_gather<<<25000, 256, 0, stream>>>(ROWPR, CSR, X2, (u32*)ACCB);
  gemm_mfma<192, 192, 1, 0, 1, 0, 1><<<391, 512, 0, stream>>>(ACCB, PWf, X1, bih, bhh,
                                                              nullptr, nullptr, nullptr, NN);

  // layer 2: gather(h1, frag out) -> G2 = h1 @ Whh^T -> fused GEMM+GRU (frag A)
  csr_gather<<<25000, 256, 0, stream>>>(ROWPR, CSR, X1, (u32*)ACCB);
  gemm_mfma<64, 192, 0, 0, 0, 0, 1><<<391, 512, 0, stream>>>(X1, PWhh, G2B, nullptr, nullptr,
                                                             nullptr, nullptr, nullptr, NN);
  gemm_mfma<192, 192, 1, 0, 2, 1, 1><<<391, 512, 0, stream>>>(ACCB, PWf, X1, bih, bhh,
                                                              G2B, X1, ACCs + 128, NN);

  // heads: fold ker-BN scale into both W1s, one KO=128 GEMM with fused dual
  // column stats, then per-head inline-BN finish.
  fold_pack<<<16, 256, 0, stream>>>(aW1, bW1, ACCs + 128, ker_g, PWab);
  gemm_mfma<64, 128, 0, 0, 0, 1, 1><<<391, 512, 0, stream>>>(X1, PWab, ACCB, nullptr, nullptr,
                                                             nullptr, nullptr, ACCs + 256, NN);
  headfin_bn<2><<<391, 256, 0, stream>>>((const u16*)ACCB, ACCs + 256, ACCs + 384,
                                         a_g, a_be, aW2, ab2, out, NN);
  headfin_bn<21><<<391, 256, 0, stream>>>((const u16*)ACCB + 64, ACCs + 320, ACCs + 448,
                                          b_g, b_be, bW2, bb2, out + (long)NN * 2, NN);
}

// Round 15
// 360.616 us; speedup vs baseline: 1.1760x; 1.0323x over previous
//
#include <hip/hip_runtime.h>

#define NN 100000
#define NE 1600000
#define NP 100096   // 391 * 256 rows, GEMM tile padding
#define NBKT 391    // ceil(NN/256) coarse buckets
#define CAP 6144    // padded region capacity per bucket
#define EPSV 1e-5f

typedef unsigned int u32;
typedef unsigned short u16;
typedef unsigned long long u64;
typedef __bf16 bf16x8 __attribute__((ext_vector_type(8)));
typedef float f32x4 __attribute__((ext_vector_type(4)));

__device__ __forceinline__ u16 f2bf(float f) {
  u32 x = __float_as_uint(f);
  return (u16)((x + 0x7FFFu + ((x >> 16) & 1u)) >> 16);  // RNE
}
__device__ __forceinline__ float bf2f(u16 h) { return __uint_as_float(((u32)h) << 16); }
__device__ __forceinline__ u32 pk2(float a, float b) {
  return (u32)f2bf(a) | ((u32)f2bf(b) << 16);
}

// ---------------- setup A: wfuse (blocks 0..143) | pack emb (144..151) | pack Whh (152..175)
__device__ __forceinline__ void pack_one(const float* W, u32* out, int K, int KOT, int i) {
  int q = i & 3, lane = (i >> 2) & 63, f = i >> 8;
  int ks = f / KOT, ot = f - ks * KOT;
  int o = ot * 16 + (lane & 15);
  int k = ks * 32 + (lane >> 4) * 8 + q * 2;
  out[i] = pk2(W[o * K + k], W[o * K + k + 1]);
}

__global__ void setupA(const float* __restrict__ relw, const float* __restrict__ Wih,
                       const float* __restrict__ embW, const float* __restrict__ Whh,
                       float* __restrict__ Wrow, u32* __restrict__ PWem, u32* __restrict__ PWhh) {
  int b = blockIdx.x;
  if (b < 144) {
    int t = b * 256 + threadIdx.x;
    if (t >= 192 * 192) return;
    int kg = t / 192, j = t % 192;
    const float* a = relw + (j >> 6) * 4096 + (j & 63) * 64;
    const float* w = Wih + kg * 64;
    float s = 0.f;
#pragma unroll
    for (int k = 0; k < 64; ++k) s += a[k] * w[k];
    Wrow[kg * 192 + j] = s;
  } else if (b < 152) {
    pack_one(embW, PWem, 64, 4, (b - 144) * 256 + threadIdx.x);
  } else {
    pack_one(Whh, PWhh, 64, 12, (b - 152) * 256 + threadIdx.x);
  }
}

__global__ void pack_wf(const float* __restrict__ Wrow, u32* __restrict__ PWf) {
  pack_one(Wrow, PWf, 192, 12, blockIdx.x * 256 + threadIdx.x);  // 72 blocks
}

// pack BOTH head weights (128 rows) folded with inline ker-BN scale
__global__ void fold_pack(const float* __restrict__ Wa, const float* __restrict__ Wb,
                          const float* __restrict__ kacc, const float* __restrict__ kg,
                          u32* __restrict__ P) {
  int i = blockIdx.x * 256 + threadIdx.x;  // 4096 = KS(2)*KOT(8)*256
  int q = i & 3, lane = (i >> 2) & 63, f = i >> 8;
  int ks = f >> 3, ot = f & 7;
  int o = ot * 16 + (lane & 15);            // 0..127
  int k = ks * 32 + (lane >> 4) * 8 + q * 2;
  const float* W = (o < 64) ? (Wa + o * 64) : (Wb + (o - 64) * 64);
  const float inv = 1.f / NN;
  float m0 = kacc[k] * inv;
  float s0 = kg[k] * rsqrtf(kacc[64 + k] * inv - m0 * m0 + EPSV);
  float m1 = kacc[k + 1] * inv;
  float s1 = kg[k + 1] * rsqrtf(kacc[64 + k + 1] * inv - m1 * m1 + EPSV);
  P[i] = pk2(W[k] * s0, W[k + 1] * s1);
}

// ---------------------------------------------------------------------------
// Hierarchical CSR build.
// record: low u32 = src(0..19) | rel(20..21) | dst&255(22..29); high u32 = norm
// ---------------------------------------------------------------------------
__global__ __launch_bounds__(256) void countplace(const int* __restrict__ src,
                                                  const int* __restrict__ dst,
                                                  const int* __restrict__ rt,
                                                  const float* __restrict__ nrm,
                                                  int* __restrict__ gcnt,
                                                  u64* __restrict__ region) {
  __shared__ u32 hist[NBKT], gbase[NBKT];
  const int t = threadIdx.x;
  for (int i = t; i < NBKT; i += 256) hist[i] = 0;
  __syncthreads();
  const int e0 = blockIdx.x * 2048 + t;
  u32 rlo[8], rhi[8], lrank[8];
  int bkt[8];
#pragma unroll
  for (int i = 0; i < 8; ++i) {
    int e = e0 + i * 256;
    bkt[i] = -1;
    if (e < NE) {
      int d = dst[e];
      int b = d >> 8;
      bkt[i] = b;
      lrank[i] = atomicAdd(&hist[b], 1u);
      rlo[i] = (u32)src[e] | ((u32)rt[e] << 20) | ((u32)(d & 255) << 22);
      rhi[i] = __float_as_uint(nrm[e]);
    }
  }
  __syncthreads();
  for (int i = t; i < NBKT; i += 256) {
    u32 h = hist[i];
    gbase[i] = h ? (u32)atomicAdd(&gcnt[i], (int)h) : 0u;
  }
  __syncthreads();
#pragma unroll
  for (int i = 0; i < 8; ++i) {
    if (bkt[i] >= 0) {
      u32 pos = gbase[bkt[i]] + lrank[i];
      if (pos < CAP)
        region[(size_t)bkt[i] * CAP + pos] = (u64)rlo[i] | ((u64)rhi[i] << 32);
    }
  }
}

// exclusive prefix over PADDED bucket sizes (gcnt + 768 slack for even-padding)
__global__ __launch_bounds__(512) void bucketscan(const int* __restrict__ gcnt,
                                                  int* __restrict__ bbase) {
  int t = threadIdx.x;
  int v = (t < NBKT) ? (gcnt[t] + 768) : 0;
  __shared__ int sh[512];
  sh[t] = v;
  __syncthreads();
#pragma unroll
  for (int off = 1; off < 512; off <<= 1) {
    int u = (t >= off) ? sh[t - off] : 0;
    __syncthreads();
    sh[t] += u;
    __syncthreads();
  }
  if (t < NBKT) bbase[t] = sh[t] - v;  // exclusive
}

// 1024-bin counting sort per bucket, each (node,rel) segment padded to EVEN
// length via zero-norm dummies. rowpr[4*node+r] = padded boundaries.
__global__ __launch_bounds__(256) void localsort(const int* __restrict__ gcnt,
                                                 const int* __restrict__ bbase,
                                                 const u64* __restrict__ region,
                                                 u64* __restrict__ csr,
                                                 int* __restrict__ rowpr) {
  const int b = blockIdx.x, t = threadIdx.x;
  int n = gcnt[b];
  if (n > CAP) n = CAP;
  const int base = bbase[b];
  __shared__ u32 hist[1024], sc[256];
#pragma unroll
  for (int i = 0; i < 4; ++i) hist[t + 256 * i] = 0;
  __syncthreads();
  for (int i = t; i < n; i += 256)
    atomicAdd(&hist[(u32)(region[(size_t)b * CAP + i] >> 20) & 1023u], 1u);
  __syncthreads();
  u32 a0 = hist[4 * t], a1 = hist[4 * t + 1], a2 = hist[4 * t + 2];
  u32 p0 = (a0 + 1) & ~1u, p1 = (a1 + 1) & ~1u, p2 = (a2 + 1) & ~1u;
  u32 part = p0 + p1 + p2;
  sc[t] = part;
  __syncthreads();
#pragma unroll
  for (int off = 1; off < 256; off <<= 1) {
    u32 u = (t >= off) ? sc[t - off] : 0;
    __syncthreads();
    sc[t] += u;
    __syncthreads();
  }
  u32 ex = sc[t] - part;
  int node = b * 256 + t;
  rowpr[4 * node + 0] = base + (int)ex;
  rowpr[4 * node + 1] = base + (int)(ex + p0);
  rowpr[4 * node + 2] = base + (int)(ex + p0 + p1);
  rowpr[4 * node + 3] = base + (int)(ex + p0 + p1 + p2);
  __syncthreads();
  hist[4 * t + 0] = ex;
  hist[4 * t + 1] = ex + p0;
  hist[4 * t + 2] = ex + p0 + p1;
  __syncthreads();
  for (int i = t; i < n; i += 256) {
    u64 rec = region[(size_t)b * CAP + i];
    u32 pos = atomicAdd(&hist[(u32)(rec >> 20) & 1023u], 1u);
    csr[(size_t)base + pos] = rec;
  }
  __syncthreads();
  if (a0 & 1) csr[(size_t)base + ex + a0] = 0ull;
  if (a1 & 1) csr[(size_t)base + ex + p0 + a1] = 0ull;
  if (a2 & 1) csr[(size_t)base + ex + p0 + p1 + a2] = 0ull;
}

// ---------------- CSR gather: wave per node, single chunk loop, positional rel
__global__ __launch_bounds__(256) void csr_gather(const int* __restrict__ rowpr,
                                                  const u64* __restrict__ csr,
                                                  const u16* __restrict__ Xbf,
                                                  u16* __restrict__ ACCbf) {
  int wv = blockIdx.x * 4 + (threadIdx.x >> 6);
  int lane = threadIdx.x & 63;
  if (wv >= NN) return;
  const int half = lane >> 5, c2 = lane & 31;
  int4 rp = *reinterpret_cast<const int4*>(rowpr + 4 * wv);
  const int b0 = __builtin_amdgcn_readfirstlane(rp.x);
  const int b1 = __builtin_amdgcn_readfirstlane(rp.y);
  const int b2 = __builtin_amdgcn_readfirstlane(rp.z);
  const int b3 = __builtin_amdgcn_readfirstlane(rp.w);
  const u32* X4 = (const u32*)Xbf;
  float a0x = 0.f, a0y = 0.f, a1x = 0.f, a1y = 0.f, a2x = 0.f, a2y = 0.f;
#define PAIRB(J, AX, AY)                                                        \
  { u32 sA = (u32)__builtin_amdgcn_readlane((int)lo, (J));                      \
    u32 sB = (u32)__builtin_amdgcn_readlane((int)lo, (J) + 1);                  \
    u32 nA = (u32)__builtin_amdgcn_readlane((int)hi, (J));                      \
    u32 nB = (u32)__builtin_amdgcn_readlane((int)hi, (J) + 1);                  \
    u32 srp = half ? sB : sA;                                                   \
    float nm = __uint_as_float(half ? nB : nA);                                 \
    u32 xw = X4[((srp & 0xFFFFFu) << 5) | (u32)c2];                             \
    AX = fmaf(__uint_as_float(xw << 16), nm, AX);                               \
    AY = fmaf(__uint_as_float(xw & 0xFFFF0000u), nm, AY); }
  for (int c = b0; c < b3; c += 64) {
    int m = b3 - c; m = m > 64 ? 64 : m;
    u32 lo = 0, hi = 0;
    if (lane < m) {
      u64 rec = csr[(size_t)c + lane];
      lo = (u32)rec; hi = (u32)(rec >> 32);
    }
    int j1 = b1 - c; j1 = j1 < 0 ? 0 : (j1 > m ? m : j1);
    int j2 = b2 - c; j2 = j2 < 0 ? 0 : (j2 > m ? m : j2);
    int j = 0;
    for (; j + 4 <= j1; j += 4) { PAIRB(j, a0x, a0y) PAIRB(j + 2, a0x, a0y) }
    if (j < j1) { PAIRB(j, a0x, a0y) j += 2; }
    for (; j + 4 <= j2; j += 4) { PAIRB(j, a1x, a1y) PAIRB(j + 2, a1x, a1y) }
    if (j < j2) { PAIRB(j, a1x, a1y) j += 2; }
    for (; j + 4 <= m; j += 4) { PAIRB(j, a2x, a2y) PAIRB(j + 2, a2x, a2y) }
    if (j < m) { PAIRB(j, a2x, a2y) j += 2; }
  }
#undef PAIRB
  a0x += __shfl_xor(a0x, 32); a0y += __shfl_xor(a0y, 32);
  a1x += __shfl_xor(a1x, 32); a1y += __shfl_xor(a1y, 32);
  a2x += __shfl_xor(a2x, 32); a2y += __shfl_xor(a2y, 32);
  if (half == 0) {
    u32* orow = (u32*)(ACCbf + (size_t)wv * 192);
    orow[c2]      = pk2(a0x, a0y);
    orow[32 + c2] = pk2(a1x, a1y);
    orow[64 + c2] = pk2(a2x, a2y);
  }
}

// ---------------------------------------------------------------------------
// MFMA GEMM: r12 structure (512 threads = 8 waves, 32 rows/wave, 256 rows/blk,
// whole-B in LDS, single barrier, A loads upfront) with ONE change:
// B staging via register load + ds_write_b128 (A/B test vs global_load_lds).
// ---------------------------------------------------------------------------
template<int K, int KO, int AF32, int GRU, int CS, int OUTBF>
__global__ __launch_bounds__(512) void gemm_mfma(
    const void* __restrict__ Av, const u32* __restrict__ Wpk, void* __restrict__ Yv,
    const float* __restrict__ bih, const float* __restrict__ bhh,
    const u16* __restrict__ G2B, const u16* __restrict__ Hv,
    float* __restrict__ csum, int n) {
  constexpr int KOT = KO / 16, KS = K / 32;
  constexpr int NFRAG = KS * KOT;
  __shared__ u32 bsh[NFRAG * 256];
  __shared__ float cs[2 * KO];
  const int lane = threadIdx.x & 63, w = threadIdx.x >> 6;  // w 0..7
  const int rr = lane & 15, kg = lane >> 4;
  const long mbase = (long)blockIdx.x * 256 + w * 32;
  const u16* Abf = (const u16*)Av;
  const float* Af = (const float*)Av;

  // ---- issue ALL A loads upfront (raw; convert later for AF32) ----
  bf16x8 abf[KS][2];
  float4 araw[AF32 ? KS : 1][2][2];
  if (AF32) {
#pragma unroll
    for (int ks = 0; ks < KS; ++ks)
#pragma unroll
      for (int hh = 0; hh < 2; ++hh) {
        long r = mbase + hh * 16 + rr;
        if (r > n - 1) r = n - 1;
        const float* pp = Af + r * K + ks * 32 + kg * 8;
        araw[ks][hh][0] = *(const float4*)pp;
        araw[ks][hh][1] = *(const float4*)(pp + 4);
      }
  } else {
#pragma unroll
    for (int ks = 0; ks < KS; ++ks)
#pragma unroll
      for (int hh = 0; hh < 2; ++hh)
        abf[ks][hh] = *reinterpret_cast<const bf16x8*>(
            Abf + (mbase + hh * 16 + rr) * K + ks * 32 + kg * 8);
  }

  // ---- stage whole B panel: reg load + ds_write (A/B vs global_load_lds) ----
  constexpr int PASSES = NFRAG / 8;
#pragma unroll
  for (int i = 0; i < PASSES; ++i) {
    int c = i * 8 + w;
    float4 bv = *reinterpret_cast<const float4*>(Wpk + (long)c * 256 + lane * 4);
    *reinterpret_cast<float4*>(&bsh[c * 256 + lane * 4]) = bv;
  }
  __syncthreads();  // drains outstanding loads/writes

  if (AF32) {
#pragma unroll
    for (int ks = 0; ks < KS; ++ks)
#pragma unroll
      for (int hh = 0; hh < 2; ++hh) {
        float4 u0 = araw[ks][hh][0], u1 = araw[ks][hh][1];
        bf16x8 o_;
        o_[0] = __builtin_bit_cast(__bf16, f2bf(u0.x));
        o_[1] = __builtin_bit_cast(__bf16, f2bf(u0.y));
        o_[2] = __builtin_bit_cast(__bf16, f2bf(u0.z));
        o_[3] = __builtin_bit_cast(__bf16, f2bf(u0.w));
        o_[4] = __builtin_bit_cast(__bf16, f2bf(u1.x));
        o_[5] = __builtin_bit_cast(__bf16, f2bf(u1.y));
        o_[6] = __builtin_bit_cast(__bf16, f2bf(u1.z));
        o_[7] = __builtin_bit_cast(__bf16, f2bf(u1.w));
        abf[ks][hh] = o_;
      }
  }

  f32x4 acc[2][KOT] = {};
#pragma unroll
  for (int ks = 0; ks < KS; ++ks) {
#pragma unroll
    for (int o = 0; o < KOT; ++o) {
      bf16x8 bfr = *reinterpret_cast<const bf16x8*>(&bsh[((ks * KOT + o) * 64 + lane) * 4]);
      acc[0][o] = __builtin_amdgcn_mfma_f32_16x16x32_bf16(abf[ks][0], bfr, acc[0][o], 0, 0, 0);
      acc[1][o] = __builtin_amdgcn_mfma_f32_16x16x32_bf16(abf[ks][1], bfr, acc[1][o], 0, 0, 0);
    }
  }

  float s[KOT] = {}, ss[KOT] = {};
  if (GRU == 0) {
#pragma unroll
    for (int tl = 0; tl < 2; ++tl)
#pragma unroll
      for (int o = 0; o < KOT; ++o)
#pragma unroll
        for (int q = 0; q < 4; ++q) {
          long row = mbase + tl * 16 + kg * 4 + q;
          float vv = acc[tl][o][q];
          if (row < n) {
            long off = row * KO + o * 16 + rr;
            if (OUTBF) ((u16*)Yv)[off] = f2bf(vv);
            else       ((float*)Yv)[off] = vv;
            if (CS) { s[o] += vv; ss[o] += vv * vv; }
          }
        }
  } else {
    float bi[12], bh_[12];
#pragma unroll
    for (int g = 0; g < 3; ++g)
#pragma unroll
      for (int o = 0; o < 4; ++o) {
        bi[g * 4 + o] = bih[g * 64 + o * 16 + rr];
        bh_[g * 4 + o] = bhh[g * 64 + o * 16 + rr];
      }
#pragma unroll
    for (int tl = 0; tl < 2; ++tl)
#pragma unroll
      for (int o = 0; o < 4; ++o) {
        int c = o * 16 + rr;
#pragma unroll
        for (int q = 0; q < 4; ++q) {
          long row = mbase + tl * 16 + kg * 4 + q;
          float ir = acc[tl][o][q] + bi[o];
          float iz = acc[tl][o + 4][q] + bi[4 + o];
          float in_ = acc[tl][o + 8][q] + bi[8 + o];
          float hr = bh_[o], hz = bh_[4 + o], hn = bh_[8 + o], hv = 0.f;
          if (GRU == 2) {
            const u16* g2 = G2B + row * 192;
            hr += bf2f(g2[c]); hz += bf2f(g2[64 + c]); hn += bf2f(g2[128 + c]);
            hv = bf2f(Hv[row * 64 + c]);
          }
          float rg = 1.f / (1.f + __expf(-(ir + hr)));
          float zg = 1.f / (1.f + __expf(-(iz + hz)));
          float ng = tanhf(in_ + rg * hn);
          float h = (1.f - zg) * ng + (GRU == 2 ? zg * hv : 0.f);
          if (row < n) {
            ((u16*)Yv)[row * 64 + c] = f2bf(h);
            if (CS) { s[o] += h; ss[o] += h * h; }
          }
        }
      }
  }
  if (CS) {
    constexpr int LIM = (GRU == 0) ? 2 * KO : 128;
    constexpr int CKO = (GRU == 0) ? KO : 64;
    constexpr int OL = (GRU == 0) ? KOT : 4;
    for (int i = threadIdx.x; i < LIM; i += 512) cs[i] = 0.f;
    __syncthreads();
#pragma unroll
    for (int o = 0; o < OL; ++o) {
      int c = o * 16 + rr;
      atomicAdd(&cs[c], s[o]);
      atomicAdd(&cs[CKO + c], ss[o]);
    }
    __syncthreads();
    for (int i = threadIdx.x; i < LIM; i += 512) atomicAdd(&csum[i], cs[i]);
  }
}

// ---------------- BN apply with inline finalize (f32 in, bf16 out) ------------
__global__ __launch_bounds__(256) void bn_apply_bf(const float* __restrict__ X,
                                                   u16* __restrict__ Y,
                                                   const float* __restrict__ accs,
                                                   const float* __restrict__ gamma,
                                                   const float* __restrict__ beta, int relu) {
  __shared__ float scsh[128];
  int t = threadIdx.x;
  if (t < 64) {
    float mean = accs[t] * (1.f / NN);
    float var = accs[64 + t] * (1.f / NN) - mean * mean;
    float sc = gamma[t] * rsqrtf(var + EPSV);
    scsh[t] = sc;
    scsh[64 + t] = beta[t] - mean * sc;
  }
  __syncthreads();
  long i = (long)blockIdx.x * 256 + t;  // NN*16 float4s
  float4 v = reinterpret_cast<const float4*>(X)[i];
  int c = (int)((i * 4) & 63);
  v.x = fmaf(v.x, scsh[c],     scsh[64 + c]);
  v.y = fmaf(v.y, scsh[c + 1], scsh[65 + c]);
  v.z = fmaf(v.z, scsh[c + 2], scsh[66 + c]);
  v.w = fmaf(v.w, scsh[c + 3], scsh[67 + c]);
  if (relu) {
    v.x = fmaxf(v.x, 0.f); v.y = fmaxf(v.y, 0.f);
    v.z = fmaxf(v.z, 0.f); v.w = fmaxf(v.w, 0.f);
  }
  reinterpret_cast<ushort4*>(Y)[i] = make_ushort4(f2bf(v.x), f2bf(v.y), f2bf(v.z), f2bf(v.w));
}

// ---------------- final head: inline BN finalize + ReLU + tiny GEMM -----------
template<int KO>
__global__ __launch_bounds__(256) void headfin_bn(const u16* __restrict__ Z,
                                                  const float* __restrict__ asum,
                                                  const float* __restrict__ asq,
                                                  const float* __restrict__ gamma,
                                                  const float* __restrict__ beta,
                                                  const float* __restrict__ W2,
                                                  const float* __restrict__ b2,
                                                  float* __restrict__ out, int n) {
  __shared__ float ws[KO * 64];
  __shared__ float scsh[128];
  int t = threadIdx.x;
  if (t < 64) {
    float mean = asum[t] * (1.f / NN);
    float var = asq[t] * (1.f / NN) - mean * mean;
    float sc = gamma[t] * rsqrtf(var + EPSV);
    scsh[t] = sc;
    scsh[64 + t] = beta[t] - mean * sc;
  }
  for (int i = t; i < KO * 64; i += 256) ws[i] = W2[i];
  __syncthreads();
  long node = (long)blockIdx.x * 256 + t;
  if (node >= n) return;
  const u16* zr = Z + node * 128;
  float x[64];
#pragma unroll
  for (int i = 0; i < 16; ++i) {
    ushort4 z4 = reinterpret_cast<const ushort4*>(zr)[i];
    int c = i * 4;
    x[c]     = fmaxf(fmaf(bf2f(z4.x), scsh[c],     scsh[64 + c]), 0.f);
    x[c + 1] = fmaxf(fmaf(bf2f(z4.y), scsh[c + 1], scsh[65 + c]), 0.f);
    x[c + 2] = fmaxf(fmaf(bf2f(z4.z), scsh[c + 2], scsh[66 + c]), 0.f);
    x[c + 3] = fmaxf(fmaf(bf2f(z4.w), scsh[c + 3], scsh[67 + c]), 0.f);
  }
#pragma unroll
  for (int o = 0; o < KO; ++o) {
    float a = b2[o];
#pragma unroll
    for (int d = 0; d < 64; ++d) a = fmaf(x[d], ws[o * 64 + d], a);
    out[node * KO + o] = a;
  }
}

extern "C" void kernel_launch(void* const* d_in, const int* in_sizes, int n_in,
                              void* d_out, int out_size, void* d_ws, size_t ws_size,
                              hipStream_t stream) {
  const float* v     = (const float*)d_in[0];
  const int*   src   = (const int*)d_in[1];
  const int*   dst   = (const int*)d_in[2];
  const int*   rt    = (const int*)d_in[3];
  const float* norm  = (const float*)d_in[4];
  const float* emb_W = (const float*)d_in[5];
  const float* emb_g  = (const float*)d_in[7];
  const float* emb_be = (const float*)d_in[8];
  const float* rel_w  = (const float*)d_in[9];
  const float* Wih    = (const float*)d_in[10];
  const float* Whh    = (const float*)d_in[11];
  const float* bih    = (const float*)d_in[12];
  const float* bhh    = (const float*)d_in[13];
  const float* ker_g  = (const float*)d_in[14];
  const float* aW1    = (const float*)d_in[16];
  const float* a_g  = (const float*)d_in[18];
  const float* a_be = (const float*)d_in[19];
  const float* aW2  = (const float*)d_in[20];
  const float* ab2  = (const float*)d_in[21];
  const float* bW1  = (const float*)d_in[22];
  const float* b_g  = (const float*)d_in[24];
  const float* b_be = (const float*)d_in[25];
  const float* bW2  = (const float*)d_in[26];
  const float* bb2  = (const float*)d_in[27];
  float* out = (float*)d_out;

  // ---- workspace carve-up ----
  char* p = (char*)d_ws;
  auto nxt = [&](size_t bytes) -> char* {
    char* r = p; p += (bytes + 255) & ~(size_t)255; return r;
  };
  int*   GCNT = (int*)nxt(512 * 4);                 // bucket counts (memset w/ ACCs)
  float* ACCs = (float*)nxt(512 * 4);               // raw BN stats: emb|ker|heads
  float* Z    = (float*)nxt((size_t)NP * 64 * 4);   // f32 emb pre-acts
  u16*   X1   = (u16*)nxt((size_t)NP * 64 * 2);     // h (bf16)
  u16*   X2   = (u16*)nxt((size_t)NP * 64 * 2);     // h0 (bf16)
  u16*   ACCB = (u16*)nxt((size_t)NP * 192 * 2);    // gathered rel-sums / head pre-acts
  u16*   G2B  = (u16*)nxt((size_t)NP * 192 * 2);    // h @ Whh^T
  u64*   REG  = (u64*)nxt((size_t)NBKT * CAP * 8);  // padded bucket regions
  u64*   CSR  = (u64*)nxt((size_t)(NE + NBKT * 768 + 64) * 8);  // even-padded CSR
  int*   BBAS = (int*)nxt(512 * 4);
  int*   ROWPR = (int*)nxt((size_t)(NP + 8) * 4 * 4); // per-(node,rel) padded bounds
  u32*   PWf  = (u32*)nxt(18432 * 4);
  u32*   PWem = (u32*)nxt(2048 * 4);
  u32*   PWhh = (u32*)nxt(6144 * 4);
  u32*   PWab = (u32*)nxt(4096 * 4);
  float* WROW = (float*)nxt(147456);

  hipMemsetAsync(GCNT, 0, 1024 * 4, stream);  // GCNT + ACCs contiguous

  // setup + hierarchical rel-sorted even-padded CSR build
  setupA<<<176, 256, 0, stream>>>(rel_w, Wih, emb_W, Whh, WROW, PWem, PWhh);
  countplace<<<782, 256, 0, stream>>>(src, dst, rt, norm, GCNT, REG);
  bucketscan<<<1, 512, 0, stream>>>(GCNT, BBAS);
  localsort<<<NBKT, 256, 0, stream>>>(GCNT, BBAS, REG, CSR, ROWPR);
  pack_wf<<<72, 256, 0, stream>>>(WROW, PWf);

  // embedding: Z = v @ emb_W^T (fused colsum); X2 = bf16(relu(BN(Z)))
  gemm_mfma<64, 64, 1, 0, 1, 0><<<391, 512, 0, stream>>>(v, PWem, Z, nullptr, nullptr,
                                                         nullptr, nullptr, ACCs + 0, NN);
  bn_apply_bf<<<6250, 256, 0, stream>>>(Z, X2, ACCs + 0, emb_g, emb_be, 1);

  // layer 1 (h==0): gather -> fused GEMM+GRU -> X1 = h1
  csr_gather<<<25000, 256, 0, stream>>>(ROWPR, CSR, X2, ACCB);
  gemm_mfma<192, 192, 0, 1, 0, 1><<<391, 512, 0, stream>>>(ACCB, PWf, X1, bih, bhh,
                                                           nullptr, nullptr, nullptr, NN);

  // layer 2: gather(h1) -> G2 = h1 @ Whh^T -> fused GEMM+GRU (+ker stats) -> X1 = h2
  csr_gather<<<25000, 256, 0, stream>>>(ROWPR, CSR, X1, ACCB);
  gemm_mfma<64, 192, 0, 0, 0, 1><<<391, 512, 0, stream>>>(X1, PWhh, G2B, nullptr, nullptr,
                                                          nullptr, nullptr, nullptr, NN);
  gemm_mfma<192, 192, 0, 2, 1, 1><<<391, 512, 0, stream>>>(ACCB, PWf, X1, bih, bhh,
                                                           G2B, X1, ACCs + 128, NN);

  // heads: fold ker-BN scale into both W1s, one KO=128 GEMM with fused dual
  // column stats, then per-head inline-BN finish.
  fold_pack<<<16, 256, 0, stream>>>(aW1, bW1, ACCs + 128, ker_g, PWab);
  gemm_mfma<64, 128, 0, 0, 1, 1><<<391, 512, 0, stream>>>(X1, PWab, ACCB, nullptr, nullptr,
                                                          nullptr, nullptr, ACCs + 256, NN);
  headfin_bn<2><<<391, 256, 0, stream>>>((const u16*)ACCB, ACCs + 256, ACCs + 384,
                                         a_g, a_be, aW2, ab2, out, NN);
  headfin_bn<21><<<391, 256, 0, stream>>>((const u16*)ACCB + 64, ACCs + 320, ACCs + 448,
                                          b_g, b_be, bW2, bb2, out + (long)NN * 2, NN);
}

// Round 16
// 356.989 us; speedup vs baseline: 1.1880x; 1.0102x over previous
//
#include <hip/hip_runtime.h>

#define NN 100000
#define NE 1600000
#define NP 100096   // 391 * 256 rows, GEMM tile padding
#define NBKT 391    // ceil(NN/256) coarse buckets
#define CAP 6144    // padded region capacity per bucket
#define EPSV 1e-5f

typedef unsigned int u32;
typedef unsigned short u16;
typedef unsigned long long u64;
typedef __bf16 bf16x8 __attribute__((ext_vector_type(8)));
typedef float f32x4 __attribute__((ext_vector_type(4)));

__device__ __forceinline__ u16 f2bf(float f) {
  u32 x = __float_as_uint(f);
  return (u16)((x + 0x7FFFu + ((x >> 16) & 1u)) >> 16);  // RNE
}
__device__ __forceinline__ float bf2f(u16 h) { return __uint_as_float(((u32)h) << 16); }
__device__ __forceinline__ u32 pk2(float a, float b) {
  return (u32)f2bf(a) | ((u32)f2bf(b) << 16);
}

// ---------------- setup A: wfuse (blocks 0..143) | pack emb (144..151) | pack Whh (152..175)
__device__ __forceinline__ void pack_one(const float* W, u32* out, int K, int KOT, int i) {
  int q = i & 3, lane = (i >> 2) & 63, f = i >> 8;
  int ks = f / KOT, ot = f - ks * KOT;
  int o = ot * 16 + (lane & 15);
  int k = ks * 32 + (lane >> 4) * 8 + q * 2;
  out[i] = pk2(W[o * K + k], W[o * K + k + 1]);
}

__global__ void setupA(const float* __restrict__ relw, const float* __restrict__ Wih,
                       const float* __restrict__ embW, const float* __restrict__ Whh,
                       float* __restrict__ Wrow, u32* __restrict__ PWem, u32* __restrict__ PWhh) {
  int b = blockIdx.x;
  if (b < 144) {
    int t = b * 256 + threadIdx.x;
    if (t >= 192 * 192) return;
    int kg = t / 192, j = t % 192;
    const float* a = relw + (j >> 6) * 4096 + (j & 63) * 64;
    const float* w = Wih + kg * 64;
    float s = 0.f;
#pragma unroll
    for (int k = 0; k < 64; ++k) s += a[k] * w[k];
    Wrow[kg * 192 + j] = s;
  } else if (b < 152) {
    pack_one(embW, PWem, 64, 4, (b - 144) * 256 + threadIdx.x);
  } else {
    pack_one(Whh, PWhh, 64, 12, (b - 152) * 256 + threadIdx.x);
  }
}

__global__ void pack_wf(const float* __restrict__ Wrow, u32* __restrict__ PWf) {
  pack_one(Wrow, PWf, 192, 12, blockIdx.x * 256 + threadIdx.x);  // 72 blocks
}

// pack BOTH head weights (128 rows) folded with inline ker-BN scale
__global__ void fold_pack(const float* __restrict__ Wa, const float* __restrict__ Wb,
                          const float* __restrict__ kacc, const float* __restrict__ kg,
                          u32* __restrict__ P) {
  int i = blockIdx.x * 256 + threadIdx.x;  // 4096 = KS(2)*KOT(8)*256
  int q = i & 3, lane = (i >> 2) & 63, f = i >> 8;
  int ks = f >> 3, ot = f & 7;
  int o = ot * 16 + (lane & 15);            // 0..127
  int k = ks * 32 + (lane >> 4) * 8 + q * 2;
  const float* W = (o < 64) ? (Wa + o * 64) : (Wb + (o - 64) * 64);
  const float inv = 1.f / NN;
  float m0 = kacc[k] * inv;
  float s0 = kg[k] * rsqrtf(kacc[64 + k] * inv - m0 * m0 + EPSV);
  float m1 = kacc[k + 1] * inv;
  float s1 = kg[k + 1] * rsqrtf(kacc[64 + k + 1] * inv - m1 * m1 + EPSV);
  P[i] = pk2(W[k] * s0, W[k + 1] * s1);
}

// ---------------------------------------------------------------------------
// Hierarchical CSR build.
// record: low u32 = src(0..19) | rel(20..21) | dst&255(22..29); high u32 = norm
// ---------------------------------------------------------------------------
__global__ __launch_bounds__(256) void countplace(const int* __restrict__ src,
                                                  const int* __restrict__ dst,
                                                  const int* __restrict__ rt,
                                                  const float* __restrict__ nrm,
                                                  int* __restrict__ gcnt,
                                                  u64* __restrict__ region) {
  __shared__ u32 hist[NBKT], gbase[NBKT];
  const int t = threadIdx.x;
  for (int i = t; i < NBKT; i += 256) hist[i] = 0;
  __syncthreads();
  const int e0 = blockIdx.x * 2048 + t;
  u32 rlo[8], rhi[8], lrank[8];
  int bkt[8];
#pragma unroll
  for (int i = 0; i < 8; ++i) {
    int e = e0 + i * 256;
    bkt[i] = -1;
    if (e < NE) {
      int d = dst[e];
      int b = d >> 8;
      bkt[i] = b;
      lrank[i] = atomicAdd(&hist[b], 1u);
      rlo[i] = (u32)src[e] | ((u32)rt[e] << 20) | ((u32)(d & 255) << 22);
      rhi[i] = __float_as_uint(nrm[e]);
    }
  }
  __syncthreads();
  for (int i = t; i < NBKT; i += 256) {
    u32 h = hist[i];
    gbase[i] = h ? (u32)atomicAdd(&gcnt[i], (int)h) : 0u;
  }
  __syncthreads();
#pragma unroll
  for (int i = 0; i < 8; ++i) {
    if (bkt[i] >= 0) {
      u32 pos = gbase[bkt[i]] + lrank[i];
      if (pos < CAP)
        region[(size_t)bkt[i] * CAP + pos] = (u64)rlo[i] | ((u64)rhi[i] << 32);
    }
  }
}

// exclusive prefix over PADDED bucket sizes (gcnt + 768 slack for even-padding)
__global__ __launch_bounds__(512) void bucketscan(const int* __restrict__ gcnt,
                                                  int* __restrict__ bbase) {
  int t = threadIdx.x;
  int v = (t < NBKT) ? (gcnt[t] + 768) : 0;
  __shared__ int sh[512];
  sh[t] = v;
  __syncthreads();
#pragma unroll
  for (int off = 1; off < 512; off <<= 1) {
    int u = (t >= off) ? sh[t - off] : 0;
    __syncthreads();
    sh[t] += u;
    __syncthreads();
  }
  if (t < NBKT) bbase[t] = sh[t] - v;  // exclusive
}

// 1024-bin counting sort per bucket, each (node,rel) segment padded to EVEN
// length via zero-norm dummies. rowpr[4*node+r] = padded boundaries.
__global__ __launch_bounds__(256) void localsort(const int* __restrict__ gcnt,
                                                 const int* __restrict__ bbase,
                                                 const u64* __restrict__ region,
                                                 u64* __restrict__ csr,
                                                 int* __restrict__ rowpr) {
  const int b = blockIdx.x, t = threadIdx.x;
  int n = gcnt[b];
  if (n > CAP) n = CAP;
  const int base = bbase[b];
  __shared__ u32 hist[1024], sc[256];
#pragma unroll
  for (int i = 0; i < 4; ++i) hist[t + 256 * i] = 0;
  __syncthreads();
  for (int i = t; i < n; i += 256)
    atomicAdd(&hist[(u32)(region[(size_t)b * CAP + i] >> 20) & 1023u], 1u);
  __syncthreads();
  u32 a0 = hist[4 * t], a1 = hist[4 * t + 1], a2 = hist[4 * t + 2];
  u32 p0 = (a0 + 1) & ~1u, p1 = (a1 + 1) & ~1u, p2 = (a2 + 1) & ~1u;
  u32 part = p0 + p1 + p2;
  sc[t] = part;
  __syncthreads();
#pragma unroll
  for (int off = 1; off < 256; off <<= 1) {
    u32 u = (t >= off) ? sc[t - off] : 0;
    __syncthreads();
    sc[t] += u;
    __syncthreads();
  }
  u32 ex = sc[t] - part;
  int node = b * 256 + t;
  rowpr[4 * node + 0] = base + (int)ex;
  rowpr[4 * node + 1] = base + (int)(ex + p0);
  rowpr[4 * node + 2] = base + (int)(ex + p0 + p1);
  rowpr[4 * node + 3] = base + (int)(ex + p0 + p1 + p2);
  __syncthreads();
  hist[4 * t + 0] = ex;
  hist[4 * t + 1] = ex + p0;
  hist[4 * t + 2] = ex + p0 + p1;
  __syncthreads();
  for (int i = t; i < n; i += 256) {
    u64 rec = region[(size_t)b * CAP + i];
    u32 pos = atomicAdd(&hist[(u32)(rec >> 20) & 1023u], 1u);
    csr[(size_t)base + pos] = rec;
  }
  __syncthreads();
  if (a0 & 1) csr[(size_t)base + ex + a0] = 0ull;
  if (a1 & 1) csr[(size_t)base + ex + p0 + a1] = 0ull;
  if (a2 & 1) csr[(size_t)base + ex + p0 + p1 + a2] = 0ull;
}

// ---------------- CSR gather: wave per node, single chunk loop, positional rel
// segments; sub-loops unrolled x4 pairs (8 edges) for 4 loads in flight.
__global__ __launch_bounds__(256) void csr_gather(const int* __restrict__ rowpr,
                                                  const u64* __restrict__ csr,
                                                  const u16* __restrict__ Xbf,
                                                  u16* __restrict__ ACCbf) {
  int wv = blockIdx.x * 4 + (threadIdx.x >> 6);
  int lane = threadIdx.x & 63;
  if (wv >= NN) return;
  const int half = lane >> 5, c2 = lane & 31;
  int4 rp = *reinterpret_cast<const int4*>(rowpr + 4 * wv);
  const int b0 = __builtin_amdgcn_readfirstlane(rp.x);
  const int b1 = __builtin_amdgcn_readfirstlane(rp.y);
  const int b2 = __builtin_amdgcn_readfirstlane(rp.z);
  const int b3 = __builtin_amdgcn_readfirstlane(rp.w);
  const u32* X4 = (const u32*)Xbf;
  float a0x = 0.f, a0y = 0.f, a1x = 0.f, a1y = 0.f, a2x = 0.f, a2y = 0.f;
#define PAIRB(J, AX, AY)                                                        \
  { u32 sA = (u32)__builtin_amdgcn_readlane((int)lo, (J));                      \
    u32 sB = (u32)__builtin_amdgcn_readlane((int)lo, (J) + 1);                  \
    u32 nA = (u32)__builtin_amdgcn_readlane((int)hi, (J));                      \
    u32 nB = (u32)__builtin_amdgcn_readlane((int)hi, (J) + 1);                  \
    u32 srp = half ? sB : sA;                                                   \
    float nm = __uint_as_float(half ? nB : nA);                                 \
    u32 xw = X4[((srp & 0xFFFFFu) << 5) | (u32)c2];                             \
    AX = fmaf(__uint_as_float(xw << 16), nm, AX);                               \
    AY = fmaf(__uint_as_float(xw & 0xFFFF0000u), nm, AY); }
#define SEGLOOP(LIM, AX, AY)                                                    \
    for (; j + 8 <= (LIM); j += 8) {                                            \
      PAIRB(j, AX, AY) PAIRB(j + 2, AX, AY)                                      \
      PAIRB(j + 4, AX, AY) PAIRB(j + 6, AX, AY)                                  \
    }                                                                            \
    if (j + 4 <= (LIM)) { PAIRB(j, AX, AY) PAIRB(j + 2, AX, AY) j += 4; }        \
    if (j < (LIM)) { PAIRB(j, AX, AY) j += 2; }
  for (int c = b0; c < b3; c += 64) {
    int m = b3 - c; m = m > 64 ? 64 : m;
    u32 lo = 0, hi = 0;
    if (lane < m) {
      u64 rec = csr[(size_t)c + lane];
      lo = (u32)rec; hi = (u32)(rec >> 32);
    }
    int j1 = b1 - c; j1 = j1 < 0 ? 0 : (j1 > m ? m : j1);
    int j2 = b2 - c; j2 = j2 < 0 ? 0 : (j2 > m ? m : j2);
    int j = 0;
    SEGLOOP(j1, a0x, a0y)
    SEGLOOP(j2, a1x, a1y)
    SEGLOOP(m, a2x, a2y)
  }
#undef SEGLOOP
#undef PAIRB
  a0x += __shfl_xor(a0x, 32); a0y += __shfl_xor(a0y, 32);
  a1x += __shfl_xor(a1x, 32); a1y += __shfl_xor(a1y, 32);
  a2x += __shfl_xor(a2x, 32); a2y += __shfl_xor(a2y, 32);
  if (half == 0) {
    u32* orow = (u32*)(ACCbf + (size_t)wv * 192);
    orow[c2]      = pk2(a0x, a0y);
    orow[32 + c2] = pk2(a1x, a1y);
    orow[64 + c2] = pk2(a2x, a2y);
  }
}

// ---------------------------------------------------------------------------
// MFMA GEMM: r15 structure (512 threads = 8 waves, 32 rows/wave, 256 rows/blk,
// whole-B in LDS via reg+ds_write, single barrier, A loads upfront).
// ---------------------------------------------------------------------------
template<int K, int KO, int AF32, int GRU, int CS, int OUTBF>
__global__ __launch_bounds__(512) void gemm_mfma(
    const void* __restrict__ Av, const u32* __restrict__ Wpk, void* __restrict__ Yv,
    const float* __restrict__ bih, const float* __restrict__ bhh,
    const u16* __restrict__ G2B, const u16* __restrict__ Hv,
    float* __restrict__ csum, int n) {
  constexpr int KOT = KO / 16, KS = K / 32;
  constexpr int NFRAG = KS * KOT;
  __shared__ u32 bsh[NFRAG * 256];
  __shared__ float cs[2 * KO];
  const int lane = threadIdx.x & 63, w = threadIdx.x >> 6;  // w 0..7
  const int rr = lane & 15, kg = lane >> 4;
  const long mbase = (long)blockIdx.x * 256 + w * 32;
  const u16* Abf = (const u16*)Av;
  const float* Af = (const float*)Av;

  // ---- issue ALL A loads upfront (raw; convert later for AF32) ----
  bf16x8 abf[KS][2];
  float4 araw[AF32 ? KS : 1][2][2];
  if (AF32) {
#pragma unroll
    for (int ks = 0; ks < KS; ++ks)
#pragma unroll
      for (int hh = 0; hh < 2; ++hh) {
        long r = mbase + hh * 16 + rr;
        if (r > n - 1) r = n - 1;
        const float* pp = Af + r * K + ks * 32 + kg * 8;
        araw[ks][hh][0] = *(const float4*)pp;
        araw[ks][hh][1] = *(const float4*)(pp + 4);
      }
  } else {
#pragma unroll
    for (int ks = 0; ks < KS; ++ks)
#pragma unroll
      for (int hh = 0; hh < 2; ++hh)
        abf[ks][hh] = *reinterpret_cast<const bf16x8*>(
            Abf + (mbase + hh * 16 + rr) * K + ks * 32 + kg * 8);
  }

  // ---- stage whole B panel: reg load + ds_write ----
  constexpr int PASSES = NFRAG / 8;
#pragma unroll
  for (int i = 0; i < PASSES; ++i) {
    int c = i * 8 + w;
    float4 bv = *reinterpret_cast<const float4*>(Wpk + (long)c * 256 + lane * 4);
    *reinterpret_cast<float4*>(&bsh[c * 256 + lane * 4]) = bv;
  }
  __syncthreads();  // drains outstanding loads/writes

  if (AF32) {
#pragma unroll
    for (int ks = 0; ks < KS; ++ks)
#pragma unroll
      for (int hh = 0; hh < 2; ++hh) {
        float4 u0 = araw[ks][hh][0], u1 = araw[ks][hh][1];
        bf16x8 o_;
        o_[0] = __builtin_bit_cast(__bf16, f2bf(u0.x));
        o_[1] = __builtin_bit_cast(__bf16, f2bf(u0.y));
        o_[2] = __builtin_bit_cast(__bf16, f2bf(u0.z));
        o_[3] = __builtin_bit_cast(__bf16, f2bf(u0.w));
        o_[4] = __builtin_bit_cast(__bf16, f2bf(u1.x));
        o_[5] = __builtin_bit_cast(__bf16, f2bf(u1.y));
        o_[6] = __builtin_bit_cast(__bf16, f2bf(u1.z));
        o_[7] = __builtin_bit_cast(__bf16, f2bf(u1.w));
        abf[ks][hh] = o_;
      }
  }

  f32x4 acc[2][KOT] = {};
#pragma unroll
  for (int ks = 0; ks < KS; ++ks) {
#pragma unroll
    for (int o = 0; o < KOT; ++o) {
      bf16x8 bfr = *reinterpret_cast<const bf16x8*>(&bsh[((ks * KOT + o) * 64 + lane) * 4]);
      acc[0][o] = __builtin_amdgcn_mfma_f32_16x16x32_bf16(abf[ks][0], bfr, acc[0][o], 0, 0, 0);
      acc[1][o] = __builtin_amdgcn_mfma_f32_16x16x32_bf16(abf[ks][1], bfr, acc[1][o], 0, 0, 0);
    }
  }

  float s[KOT] = {}, ss[KOT] = {};
  if (GRU == 0) {
#pragma unroll
    for (int tl = 0; tl < 2; ++tl)
#pragma unroll
      for (int o = 0; o < KOT; ++o)
#pragma unroll
        for (int q = 0; q < 4; ++q) {
          long row = mbase + tl * 16 + kg * 4 + q;
          float vv = acc[tl][o][q];
          if (row < n) {
            long off = row * KO + o * 16 + rr;
            if (OUTBF) ((u16*)Yv)[off] = f2bf(vv);
            else       ((float*)Yv)[off] = vv;
            if (CS) { s[o] += vv; ss[o] += vv * vv; }
          }
        }
  } else {
    float bi[12], bh_[12];
#pragma unroll
    for (int g = 0; g < 3; ++g)
#pragma unroll
      for (int o = 0; o < 4; ++o) {
        bi[g * 4 + o] = bih[g * 64 + o * 16 + rr];
        bh_[g * 4 + o] = bhh[g * 64 + o * 16 + rr];
      }
#pragma unroll
    for (int tl = 0; tl < 2; ++tl)
#pragma unroll
      for (int o = 0; o < 4; ++o) {
        int c = o * 16 + rr;
#pragma unroll
        for (int q = 0; q < 4; ++q) {
          long row = mbase + tl * 16 + kg * 4 + q;
          float ir = acc[tl][o][q] + bi[o];
          float iz = acc[tl][o + 4][q] + bi[4 + o];
          float in_ = acc[tl][o + 8][q] + bi[8 + o];
          float hr = bh_[o], hz = bh_[4 + o], hn = bh_[8 + o], hv = 0.f;
          if (GRU == 2) {
            const u16* g2 = G2B + row * 192;
            hr += bf2f(g2[c]); hz += bf2f(g2[64 + c]); hn += bf2f(g2[128 + c]);
            hv = bf2f(Hv[row * 64 + c]);
          }
          float rg = 1.f / (1.f + __expf(-(ir + hr)));
          float zg = 1.f / (1.f + __expf(-(iz + hz)));
          float ng = tanhf(in_ + rg * hn);
          float h = (1.f - zg) * ng + (GRU == 2 ? zg * hv : 0.f);
          if (row < n) {
            ((u16*)Yv)[row * 64 + c] = f2bf(h);
            if (CS) { s[o] += h; ss[o] += h * h; }
          }
        }
      }
  }
  if (CS) {
    constexpr int LIM = (GRU == 0) ? 2 * KO : 128;
    constexpr int CKO = (GRU == 0) ? KO : 64;
    constexpr int OL = (GRU == 0) ? KOT : 4;
    for (int i = threadIdx.x; i < LIM; i += 512) cs[i] = 0.f;
    __syncthreads();
#pragma unroll
    for (int o = 0; o < OL; ++o) {
      int c = o * 16 + rr;
      atomicAdd(&cs[c], s[o]);
      atomicAdd(&cs[CKO + c], ss[o]);
    }
    __syncthreads();
    for (int i = threadIdx.x; i < LIM; i += 512) atomicAdd(&csum[i], cs[i]);
  }
}

// ---------------- BN apply with inline finalize (f32 in, bf16 out) ------------
__global__ __launch_bounds__(256) void bn_apply_bf(const float* __restrict__ X,
                                                   u16* __restrict__ Y,
                                                   const float* __restrict__ accs,
                                                   const float* __restrict__ gamma,
                                                   const float* __restrict__ beta, int relu) {
  __shared__ float scsh[128];
  int t = threadIdx.x;
  if (t < 64) {
    float mean = accs[t] * (1.f / NN);
    float var = accs[64 + t] * (1.f / NN) - mean * mean;
    float sc = gamma[t] * rsqrtf(var + EPSV);
    scsh[t] = sc;
    scsh[64 + t] = beta[t] - mean * sc;
  }
  __syncthreads();
  long i = (long)blockIdx.x * 256 + t;  // NN*16 float4s
  float4 v = reinterpret_cast<const float4*>(X)[i];
  int c = (int)((i * 4) & 63);
  v.x = fmaf(v.x, scsh[c],     scsh[64 + c]);
  v.y = fmaf(v.y, scsh[c + 1], scsh[65 + c]);
  v.z = fmaf(v.z, scsh[c + 2], scsh[66 + c]);
  v.w = fmaf(v.w, scsh[c + 3], scsh[67 + c]);
  if (relu) {
    v.x = fmaxf(v.x, 0.f); v.y = fmaxf(v.y, 0.f);
    v.z = fmaxf(v.z, 0.f); v.w = fmaxf(v.w, 0.f);
  }
  reinterpret_cast<ushort4*>(Y)[i] = make_ushort4(f2bf(v.x), f2bf(v.y), f2bf(v.z), f2bf(v.w));
}

// ---------------- final head: inline BN finalize + ReLU + tiny GEMM -----------
template<int KO>
__global__ __launch_bounds__(256) void headfin_bn(const u16* __restrict__ Z,
                                                  const float* __restrict__ asum,
                                                  const float* __restrict__ asq,
                                                  const float* __restrict__ gamma,
                                                  const float* __restrict__ beta,
                                                  const float* __restrict__ W2,
                                                  const float* __restrict__ b2,
                                                  float* __restrict__ out, int n) {
  __shared__ float ws[KO * 64];
  __shared__ float scsh[128];
  int t = threadIdx.x;
  if (t < 64) {
    float mean = asum[t] * (1.f / NN);
    float var = asq[t] * (1.f / NN) - mean * mean;
    float sc = gamma[t] * rsqrtf(var + EPSV);
    scsh[t] = sc;
    scsh[64 + t] = beta[t] - mean * sc;
  }
  for (int i = t; i < KO * 64; i += 256) ws[i] = W2[i];
  __syncthreads();
  long node = (long)blockIdx.x * 256 + t;
  if (node >= n) return;
  const u16* zr = Z + node * 128;
  float x[64];
#pragma unroll
  for (int i = 0; i < 16; ++i) {
    ushort4 z4 = reinterpret_cast<const ushort4*>(zr)[i];
    int c = i * 4;
    x[c]     = fmaxf(fmaf(bf2f(z4.x), scsh[c],     scsh[64 + c]), 0.f);
    x[c + 1] = fmaxf(fmaf(bf2f(z4.y), scsh[c + 1], scsh[65 + c]), 0.f);
    x[c + 2] = fmaxf(fmaf(bf2f(z4.z), scsh[c + 2], scsh[66 + c]), 0.f);
    x[c + 3] = fmaxf(fmaf(bf2f(z4.w), scsh[c + 3], scsh[67 + c]), 0.f);
  }
#pragma unroll
  for (int o = 0; o < KO; ++o) {
    float a = b2[o];
#pragma unroll
    for (int d = 0; d < 64; ++d) a = fmaf(x[d], ws[o * 64 + d], a);
    out[node * KO + o] = a;
  }
}

extern "C" void kernel_launch(void* const* d_in, const int* in_sizes, int n_in,
                              void* d_out, int out_size, void* d_ws, size_t ws_size,
                              hipStream_t stream) {
  const float* v     = (const float*)d_in[0];
  const int*   src   = (const int*)d_in[1];
  const int*   dst   = (const int*)d_in[2];
  const int*   rt    = (const int*)d_in[3];
  const float* norm  = (const float*)d_in[4];
  const float* emb_W = (const float*)d_in[5];
  const float* emb_g  = (const float*)d_in[7];
  const float* emb_be = (const float*)d_in[8];
  const float* rel_w  = (const float*)d_in[9];
  const float* Wih    = (const float*)d_in[10];
  const float* Whh    = (const float*)d_in[11];
  const float* bih    = (const float*)d_in[12];
  const float* bhh    = (const float*)d_in[13];
  const float* ker_g  = (const float*)d_in[14];
  const float* aW1    = (const float*)d_in[16];
  const float* a_g  = (const float*)d_in[18];
  const float* a_be = (const float*)d_in[19];
  const float* aW2  = (const float*)d_in[20];
  const float* ab2  = (const float*)d_in[21];
  const float* bW1  = (const float*)d_in[22];
  const float* b_g  = (const float*)d_in[24];
  const float* b_be = (const float*)d_in[25];
  const float* bW2  = (const float*)d_in[26];
  const float* bb2  = (const float*)d_in[27];
  float* out = (float*)d_out;

  // ---- workspace carve-up ----
  char* p = (char*)d_ws;
  auto nxt = [&](size_t bytes) -> char* {
    char* r = p; p += (bytes + 255) & ~(size_t)255; return r;
  };
  int*   GCNT = (int*)nxt(512 * 4);                 // bucket counts (memset w/ ACCs)
  float* ACCs = (float*)nxt(512 * 4);               // raw BN stats: emb|ker|heads
  float* Z    = (float*)nxt((size_t)NP * 64 * 4);   // f32 emb pre-acts
  u16*   X1   = (u16*)nxt((size_t)NP * 64 * 2);     // h (bf16)
  u16*   X2   = (u16*)nxt((size_t)NP * 64 * 2);     // h0 (bf16)
  u16*   ACCB = (u16*)nxt((size_t)NP * 192 * 2);    // gathered rel-sums / head pre-acts
  u16*   G2B  = (u16*)nxt((size_t)NP * 192 * 2);    // h @ Whh^T
  u64*   REG  = (u64*)nxt((size_t)NBKT * CAP * 8);  // padded bucket regions
  u64*   CSR  = (u64*)nxt((size_t)(NE + NBKT * 768 + 64) * 8);  // even-padded CSR
  int*   BBAS = (int*)nxt(512 * 4);
  int*   ROWPR = (int*)nxt((size_t)(NP + 8) * 4 * 4); // per-(node,rel) padded bounds
  u32*   PWf  = (u32*)nxt(18432 * 4);
  u32*   PWem = (u32*)nxt(2048 * 4);
  u32*   PWhh = (u32*)nxt(6144 * 4);
  u32*   PWab = (u32*)nxt(4096 * 4);
  float* WROW = (float*)nxt(147456);

  hipMemsetAsync(GCNT, 0, 1024 * 4, stream);  // GCNT + ACCs contiguous

  // setup + hierarchical rel-sorted even-padded CSR build
  setupA<<<176, 256, 0, stream>>>(rel_w, Wih, emb_W, Whh, WROW, PWem, PWhh);
  countplace<<<782, 256, 0, stream>>>(src, dst, rt, norm, GCNT, REG);
  bucketscan<<<1, 512, 0, stream>>>(GCNT, BBAS);
  localsort<<<NBKT, 256, 0, stream>>>(GCNT, BBAS, REG, CSR, ROWPR);
  pack_wf<<<72, 256, 0, stream>>>(WROW, PWf);

  // embedding: Z = v @ emb_W^T (fused colsum); X2 = bf16(relu(BN(Z)))
  gemm_mfma<64, 64, 1, 0, 1, 0><<<391, 512, 0, stream>>>(v, PWem, Z, nullptr, nullptr,
                                                         nullptr, nullptr, ACCs + 0, NN);
  bn_apply_bf<<<6250, 256, 0, stream>>>(Z, X2, ACCs + 0, emb_g, emb_be, 1);

  // layer 1 (h==0): gather -> fused GEMM+GRU -> X1 = h1
  csr_gather<<<25000, 256, 0, stream>>>(ROWPR, CSR, X2, ACCB);
  gemm_mfma<192, 192, 0, 1, 0, 1><<<391, 512, 0, stream>>>(ACCB, PWf, X1, bih, bhh,
                                                           nullptr, nullptr, nullptr, NN);

  // layer 2: gather(h1) -> G2 = h1 @ Whh^T -> fused GEMM+GRU (+ker stats) -> X1 = h2
  csr_gather<<<25000, 256, 0, stream>>>(ROWPR, CSR, X1, ACCB);
  gemm_mfma<64, 192, 0, 0, 0, 1><<<391, 512, 0, stream>>>(X1, PWhh, G2B, nullptr, nullptr,
                                                          nullptr, nullptr, nullptr, NN);
  gemm_mfma<192, 192, 0, 2, 1, 1><<<391, 512, 0, stream>>>(ACCB, PWf, X1, bih, bhh,
                                                           G2B, X1, ACCs + 128, NN);

  // heads: fold ker-BN scale into both W1s, one KO=128 GEMM with fused dual
  // column stats, then per-head inline-BN finish.
  fold_pack<<<16, 256, 0, stream>>>(aW1, bW1, ACCs + 128, ker_g, PWab);
  gemm_mfma<64, 128, 0, 0, 1, 1><<<391, 512, 0, stream>>>(X1, PWab, ACCB, nullptr, nullptr,
                                                          nullptr, nullptr, ACCs + 256, NN);
  headfin_bn<2><<<391, 256, 0, stream>>>((const u16*)ACCB, ACCs + 256, ACCs + 384,
                                         a_g, a_be, aW2, ab2, out, NN);
  headfin_bn<21><<<391, 256, 0, stream>>>((const u16*)ACCB + 64, ACCs + 320, ACCs + 448,
                                          b_g, b_be, bW2, bb2, out + (long)NN * 2, NN);
}